// Round 3
// baseline (2901.348 us; speedup 1.0000x reference)
//
#include <hip/hip_runtime.h>

#define B_ 32
#define P_ 2048
#define K_ 20

// ---- order-preserving (key, idx) packing -------------------------------
// larger key wins; ties -> smaller idx wins (matches jax.lax.top_k).
__device__ inline unsigned long long pack_key(float key, int j) {
  unsigned u = __float_as_uint(key);
  unsigned m = ((unsigned)((int)u >> 31)) | 0x80000000u;
  u ^= m;  // monotone float->uint
  return ((unsigned long long)u << 32) | (unsigned)(~j);
}

// Sorted-ascending top-K list (t[0]=worst, t[K-1]=best), in registers.
__device__ inline void topk_insert(unsigned long long (&t)[K_],
                                   unsigned long long x) {
  if (x > t[0]) {
#pragma unroll
    for (int p = 0; p < K_ - 1; ++p) {
      bool c = x > t[p + 1];                       // x belongs above slot p
      unsigned long long mx = t[p] > x ? t[p] : x; // max(old[p], x)
      t[p] = c ? t[p + 1] : mx;
    }
    t[K_ - 1] = t[K_ - 1] > x ? t[K_ - 1] : x;
  }
}

// ---------------- Kernel 1: kNN on 3-D positions -> idx1 ----------------
// grid (P/128, B), block 256: 128 rows x 2 j-halves. Bitonic merge via LDS.
__global__ __launch_bounds__(256) void knn3_kernel(
    const float* __restrict__ pos, int* __restrict__ idx) {
  __shared__ float4 pts[P_];                         // 32 KB: x,y,z,d2
  __shared__ unsigned long long lists[128][K_];      // 20 KB: half-1 lists
  int b = blockIdx.y;
  const float* bp = pos + (size_t)b * P_ * 3;
  for (int j = threadIdx.x; j < P_; j += 256) {
    float x = bp[j * 3 + 0], y = bp[j * 3 + 1], z = bp[j * 3 + 2];
    pts[j] = make_float4(x, y, z, x * x + y * y + z * z);
  }
  __syncthreads();
  int q = threadIdx.x & 127;           // row within block
  int h = threadIdx.x >> 7;            // j-half
  int r = blockIdx.x * 128 + q;        // global row
  float4 pi = pts[r];
  unsigned long long t[K_];
#pragma unroll
  for (int k = 0; k < K_; ++k) t[k] = 0ULL;
  int j0 = h * (P_ / 2);
  for (int j = j0; j < j0 + P_ / 2; ++j) {
    float4 pj = pts[j];  // LDS broadcast
    float key = 2.f * (pi.x * pj.x + pi.y * pj.y + pi.z * pj.z) - pj.w;
    topk_insert(t, pack_key(key, j));
  }
  if (h == 1) {
#pragma unroll
    for (int k = 0; k < K_; ++k) lists[q][k] = t[k];
  }
  __syncthreads();
  if (h == 0) {
    int* op = idx + ((size_t)b * P_ + r) * K_;
#pragma unroll
    for (int k = 0; k < K_; ++k) {
      unsigned long long o = lists[q][K_ - 1 - k];
      unsigned long long m = t[k] > o ? t[k] : o;   // bitonic top-K merge
      op[k] = (int)(~(unsigned)m);
    }
  }
}

// ---------------- Kernel 2: bv1[i][c] = pos_i @ W1[3:6] ----------------
__global__ __launch_bounds__(256) void bv1_kernel(
    const float* __restrict__ pos, const float* __restrict__ W1,
    float* __restrict__ bv) {
  int t = blockIdx.x * 256 + threadIdx.x;  // over B*P*64
  int c = t & 63, i = t >> 6;
  const float* p = pos + (size_t)i * 3;
  bv[t] = p[0] * W1[3 * 64 + c] + p[1] * W1[4 * 64 + c] + p[2] * W1[5 * 64 + c];
}

// ---------------- Kernel 3: layer-1 edge MLP + max over K -> x1, d2 -----
__global__ __launch_bounds__(256) void layer1_kernel(
    const float* __restrict__ pos, const float* __restrict__ W1,
    const float* __restrict__ b1, const float* __restrict__ g1,
    const float* __restrict__ bt1, const float* __restrict__ W2,
    const float* __restrict__ b2, const int* __restrict__ idx,
    const float* __restrict__ bv, float* __restrict__ x1,
    float* __restrict__ d2out) {
  __shared__ __align__(16) float W2t[64 * 68];  // W2t[n][c] = W2[c][n]
  __shared__ __align__(16) float T[4][K_ * 64];
  int b = blockIdx.y;
  int lane = threadIdx.x & 63;
  int w = threadIdx.x >> 6;
  for (int t = threadIdx.x; t < 64 * 64; t += 256) {
    int c = t >> 6, n = t & 63;
    W2t[n * 68 + c] = W2[c * 64 + n];
  }
  int i = blockIdx.x * 4 + w;
  size_t ip = (size_t)b * P_ + i;
  const float* posi = pos + ip * 3;
  float px = posi[0], py = posi[1], pz = posi[2];
  int c = lane;
  float cv = px * (W1[0 * 64 + c] - W1[3 * 64 + c]) +
             py * (W1[1 * 64 + c] - W1[4 * 64 + c]) +
             pz * (W1[2 * 64 + c] - W1[5 * 64 + c]) + b1[c];
  float g = g1[c], bt = bt1[c];
  const int* ji = idx + ip * K_;
  const float* bvb = bv + (size_t)b * P_ * 64;
  for (int k = 0; k < K_; ++k) {
    int j = ji[k];
    float t = cv + bvb[(size_t)j * 64 + c];
    t = fmaxf(t * g + bt, 0.f);
    T[w][k * 64 + c] = t;
  }
  __syncthreads();
  float acc[K_];
#pragma unroll
  for (int k = 0; k < K_; ++k) acc[k] = 0.f;
  const float4* Trow = (const float4*)&T[w][0];
#pragma unroll
  for (int c4 = 0; c4 < 16; ++c4) {
    float4 wv = *(const float4*)&W2t[lane * 68 + c4 * 4];
#pragma unroll
    for (int k = 0; k < K_; ++k) {
      float4 tvv = Trow[k * 16 + c4];  // broadcast
      acc[k] += tvv.x * wv.x + tvv.y * wv.y + tvv.z * wv.z + tvv.w * wv.w;
    }
  }
  float m = -INFINITY;
#pragma unroll
  for (int k = 0; k < K_; ++k) m = fmaxf(m, acc[k]);
  m += b2[lane];
  x1[ip * 64 + lane] = m;
  float s = m * m;
#pragma unroll
  for (int off = 32; off; off >>= 1) s += __shfl_xor(s, off, 64);
  if (lane == 0) d2out[ip] = s;
}

// ---------------- Kernel 4: kNN on 64-D x1 -> idx2 (tiled Gram) ---------
// grid (P/128, B), block 256. Per block: 128 rows; loop 16 col-tiles of 128.
// Phase G: 8x8 register-tiled fp32 GEMM -> C tile in LDS (keys).
// Phase S: 2 threads/row scan the tile with the proven u64 top-K chain.
__global__ __launch_bounds__(256) void knn64_kernel(
    const float* __restrict__ x1, const float* __restrict__ d2g,
    int* __restrict__ idx) {
  __shared__ __align__(16) float As[128 * 68];   // 34,816 B
  __shared__ __align__(16) float Bs[128 * 68];   // 34,816 B
  __shared__ __align__(16) float Cs[128 * 132];  // 67,584 B (lists overlay)
  __shared__ float d2s[128];
  int b = blockIdx.y;
  int r0 = blockIdx.x * 128;
  const float* xb = x1 + (size_t)b * P_ * 64;

  // stage A: rows r0..r0+127
  for (int g = threadIdx.x; g < 128 * 16; g += 256) {
    int r = g >> 4, c4 = g & 15;
    float4 v = *(const float4*)(xb + (size_t)(r0 + r) * 64 + c4 * 4);
    *(float4*)(&As[r * 68 + c4 * 4]) = v;
  }

  int tr = threadIdx.x >> 4;   // 0..15, rows tr*8..tr*8+7
  int tc = threadIdx.x & 15;   // 0..15, cols tc + 16*cc
  int q = threadIdx.x & 127;   // select row
  int h = threadIdx.x >> 7;    // select col-half
  unsigned long long t[K_];
#pragma unroll
  for (int k = 0; k < K_; ++k) t[k] = 0ULL;

#pragma unroll 1
  for (int tile = 0; tile < 16; ++tile) {
    int j0 = tile * 128;
    __syncthreads();  // select(tile-1) done; safe to overwrite Bs
    for (int g = threadIdx.x; g < 128 * 16; g += 256) {
      int r = g >> 4, c4 = g & 15;
      float4 v = *(const float4*)(xb + (size_t)(j0 + r) * 64 + c4 * 4);
      *(float4*)(&Bs[r * 68 + c4 * 4]) = v;
    }
    if (threadIdx.x < 128) d2s[threadIdx.x] = d2g[(size_t)b * P_ + j0 + threadIdx.x];
    __syncthreads();  // A,B,d2 staged

    // ---- GEMM phase: 8x8 per thread ----
    float acc[8][8];
#pragma unroll
    for (int a = 0; a < 8; ++a)
#pragma unroll
      for (int c = 0; c < 8; ++c) acc[a][c] = 0.f;
#pragma unroll
    for (int c4 = 0; c4 < 16; ++c4) {
      float4 af[8], bf[8];
#pragma unroll
      for (int a = 0; a < 8; ++a)
        af[a] = *(const float4*)(&As[(tr * 8 + a) * 68 + c4 * 4]);
#pragma unroll
      for (int c = 0; c < 8; ++c)
        bf[c] = *(const float4*)(&Bs[(tc + 16 * c) * 68 + c4 * 4]);
#pragma unroll
      for (int a = 0; a < 8; ++a)
#pragma unroll
        for (int c = 0; c < 8; ++c) {
          float s = acc[a][c];
          s = fmaf(af[a].x, bf[c].x, s);
          s = fmaf(af[a].y, bf[c].y, s);
          s = fmaf(af[a].z, bf[c].z, s);
          s = fmaf(af[a].w, bf[c].w, s);
          acc[a][c] = s;
        }
    }
#pragma unroll
    for (int a = 0; a < 8; ++a)
#pragma unroll
      for (int c = 0; c < 8; ++c) {
        int col = tc + 16 * c;
        Cs[(tr * 8 + a) * 132 + col] = 2.f * acc[a][c] - d2s[col];
      }
    __syncthreads();  // C tile ready

    // ---- Select phase: row q, cols h*64..h*64+63 of this tile ----
    const float* crow = &Cs[q * 132 + h * 64];
#pragma unroll
    for (int g4 = 0; g4 < 16; ++g4) {
      float4 kv = *(const float4*)(crow + g4 * 4);
      int jg = j0 + h * 64 + g4 * 4;
      topk_insert(t, pack_key(kv.x, jg + 0));
      topk_insert(t, pack_key(kv.y, jg + 1));
      topk_insert(t, pack_key(kv.z, jg + 2));
      topk_insert(t, pack_key(kv.w, jg + 3));
    }
  }

  __syncthreads();
  unsigned long long* lists = (unsigned long long*)Cs;  // overlay
  if (h == 1) {
#pragma unroll
    for (int k = 0; k < K_; ++k) lists[q * K_ + k] = t[k];
  }
  __syncthreads();
  if (h == 0) {
    int* op = idx + ((size_t)b * P_ + r0 + q) * K_;
#pragma unroll
    for (int k = 0; k < K_; ++k) {
      unsigned long long o = lists[q * K_ + (K_ - 1 - k)];
      unsigned long long m = t[k] > o ? t[k] : o;  // bitonic top-K merge
      op[k] = (int)(~(unsigned)m);
    }
  }
}

// ---------------- Kernel 5: e2 = x1@(W3a-W3b)+b3, bb2 = x1@W3b ----------
__global__ __launch_bounds__(256) void ebb_kernel(
    const float* __restrict__ x1, const float* __restrict__ W3,
    const float* __restrict__ b3, float* __restrict__ e2,
    float* __restrict__ bb2) {
  __shared__ float xs[16 * 64];
  size_t p0 = (size_t)blockIdx.x * 16;
  for (int v = threadIdx.x; v < 16 * 64; v += 256) xs[v] = x1[p0 * 64 + v];
  __syncthreads();
  int n = threadIdx.x & 127;
  int which = threadIdx.x >> 7;  // wave-uniform
  float acc[16];
#pragma unroll
  for (int p = 0; p < 16; ++p) acc[p] = 0.f;
  for (int c = 0; c < 64; ++c) {
    float wa = W3[c * 128 + n];
    float wb = W3[(64 + c) * 128 + n];
    float wv = which ? wb : (wa - wb);
#pragma unroll
    for (int p = 0; p < 16; ++p) acc[p] += xs[p * 64 + c] * wv;
  }
  float bias = which ? 0.f : b3[n];
  float* dst = which ? bb2 : e2;
#pragma unroll
  for (int p = 0; p < 16; ++p) dst[(p0 + p) * 128 + n] = acc[p] + bias;
}

// ---------------- Kernel 6: x2 gather-max + hp@Wl + per-tile max --------
__global__ __launch_bounds__(256) void final_kernel(
    const float* __restrict__ x1, const float* __restrict__ e2,
    const float* __restrict__ bb2, const int* __restrict__ idx,
    const float* __restrict__ Wl, const float* __restrict__ bl,
    float* __restrict__ partial) {
  __shared__ float hp[32][192];
  __shared__ float smax[2][128];
  int b = blockIdx.y;
  int i0 = blockIdx.x * 32;
  size_t gp0 = (size_t)b * P_ + i0;
  for (int v = threadIdx.x; v < 32 * 64; v += 256) {
    int p = v >> 6, c = v & 63;
    hp[p][c] = x1[(gp0 + p) * 64 + c];
  }
  for (int v = threadIdx.x; v < 32 * 128; v += 256) {
    int p = v >> 7, n = v & 127;
    size_t gp = gp0 + p;
    const int* ji = idx + gp * K_;
    float m = -INFINITY;
    for (int k = 0; k < K_; ++k) {
      int j = ji[k];
      m = fmaxf(m, bb2[((size_t)b * P_ + j) * 128 + n]);
    }
    hp[p][64 + n] = e2[gp * 128 + n] + m;
  }
  __syncthreads();
  int n = threadIdx.x & 127;
  int pg = threadIdx.x >> 7;
  float acc[16];
#pragma unroll
  for (int p = 0; p < 16; ++p) acc[p] = 0.f;
  for (int c = 0; c < 192; ++c) {
    float wv = Wl[c * 128 + n];
#pragma unroll
    for (int p = 0; p < 16; ++p) acc[p] += hp[pg * 16 + p][c] * wv;
  }
  float m = -INFINITY;
#pragma unroll
  for (int p = 0; p < 16; ++p) m = fmaxf(m, acc[p]);
  smax[pg][n] = m;
  __syncthreads();
  if (threadIdx.x < 128) {
    float v = fmaxf(smax[0][n], smax[1][n]) + bl[n];
    partial[((size_t)b * 64 + blockIdx.x) * 128 + n] = v;
  }
}

// ---------------- Kernel 7: reduce partial maxes -> out (B,128) ---------
__global__ __launch_bounds__(256) void reduce_kernel(
    const float* __restrict__ partial, float* __restrict__ out) {
  int t = blockIdx.x * 256 + threadIdx.x;  // 4096
  int b = t >> 7, n = t & 127;
  float m = -INFINITY;
  for (int tb = 0; tb < 64; ++tb)
    m = fmaxf(m, partial[((size_t)b * 64 + tb) * 128 + n]);
  out[t] = m;
}

extern "C" void kernel_launch(void* const* d_in, const int* in_sizes, int n_in,
                              void* d_out, int out_size, void* d_ws,
                              size_t ws_size, hipStream_t stream) {
  (void)in_sizes; (void)n_in; (void)out_size; (void)ws_size;
  const float* pos = (const float*)d_in[0];
  const float* W1  = (const float*)d_in[1];
  const float* b1  = (const float*)d_in[2];
  const float* g1  = (const float*)d_in[3];
  const float* bt1 = (const float*)d_in[4];
  const float* W2  = (const float*)d_in[5];
  const float* b2  = (const float*)d_in[6];
  const float* W3  = (const float*)d_in[7];
  const float* b3  = (const float*)d_in[8];
  const float* Wl  = (const float*)d_in[9];
  const float* bl  = (const float*)d_in[10];
  float* out = (float*)d_out;

  // Workspace layout (bytes). Peak ~86.3 MB.
  char* w = (char*)d_ws;
  int*   idxp  = (int*)(w + 0);             //  5,242,880  idx1 then idx2
  float* x1p   = (float*)(w + 5242880);     // 16,777,216
  float* bv1p  = (float*)(w + 22020096);    // 33,554,432 region: bv1 then bb2
  float* bb2p  = bv1p;
  float* d2p   = (float*)(w + 55574528);    //    262,144
  float* e2p   = (float*)(w + 55836672);    // 33,554,432
  float* partp = (float*)(w + 89391104);    //  1,048,576

  knn3_kernel<<<dim3(P_ / 128, B_), 256, 0, stream>>>(pos, idxp);
  bv1_kernel<<<dim3(B_ * P_ * 64 / 256), 256, 0, stream>>>(pos, W1, bv1p);
  layer1_kernel<<<dim3(P_ / 4, B_), 256, 0, stream>>>(
      pos, W1, b1, g1, bt1, W2, b2, idxp, bv1p, x1p, d2p);
  knn64_kernel<<<dim3(P_ / 128, B_), 256, 0, stream>>>(x1p, d2p, idxp);
  ebb_kernel<<<dim3(B_ * P_ / 16), 256, 0, stream>>>(x1p, W3, b3, e2p, bb2p);
  final_kernel<<<dim3(P_ / 32, B_), 256, 0, stream>>>(
      x1p, e2p, bb2p, idxp, Wl, bl, partp);
  reduce_kernel<<<dim3(16), 256, 0, stream>>>(partp, out);
}

// Round 4
// 1941.515 us; speedup vs baseline: 1.4944x; 1.4944x over previous
//
#include <hip/hip_runtime.h>

#define B_ 32
#define P_ 2048
#define K_ 20

// ---- order-preserving (key, idx) packing -------------------------------
// larger key wins; ties -> smaller idx wins (matches jax.lax.top_k).
__device__ inline unsigned long long pack_key(float key, int j) {
  unsigned u = __float_as_uint(key);
  unsigned m = ((unsigned)((int)u >> 31)) | 0x80000000u;
  u ^= m;  // monotone float->uint
  return ((unsigned long long)u << 32) | (unsigned)(~j);
}

// Sorted-ascending top-K list (t[0]=worst, t[K-1]=best), in registers.
// (used by knn3; knn64 uses the wave-distributed variant)
__device__ inline void topk_insert(unsigned long long (&t)[K_],
                                   unsigned long long x) {
  if (x > t[0]) {
#pragma unroll
    for (int p = 0; p < K_ - 1; ++p) {
      bool c = x > t[p + 1];                       // x belongs above slot p
      unsigned long long mx = t[p] > x ? t[p] : x; // max(old[p], x)
      t[p] = c ? t[p + 1] : mx;
    }
    t[K_ - 1] = t[K_ - 1] > x ? t[K_ - 1] : x;
  }
}

// ---------------- Kernel 1: kNN on 3-D positions -> idx1 ----------------
// grid (P/128, B), block 256: 128 rows x 2 j-halves. Bitonic merge via LDS.
__global__ __launch_bounds__(256) void knn3_kernel(
    const float* __restrict__ pos, int* __restrict__ idx) {
  __shared__ float4 pts[P_];                         // 32 KB: x,y,z,d2
  __shared__ unsigned long long lists[128][K_];      // 20 KB: half-1 lists
  int b = blockIdx.y;
  const float* bp = pos + (size_t)b * P_ * 3;
  for (int j = threadIdx.x; j < P_; j += 256) {
    float x = bp[j * 3 + 0], y = bp[j * 3 + 1], z = bp[j * 3 + 2];
    pts[j] = make_float4(x, y, z, x * x + y * y + z * z);
  }
  __syncthreads();
  int q = threadIdx.x & 127;           // row within block
  int h = threadIdx.x >> 7;            // j-half
  int r = blockIdx.x * 128 + q;        // global row
  float4 pi = pts[r];
  unsigned long long t[K_];
#pragma unroll
  for (int k = 0; k < K_; ++k) t[k] = 0ULL;
  int j0 = h * (P_ / 2);
  for (int j = j0; j < j0 + P_ / 2; ++j) {
    float4 pj = pts[j];  // LDS broadcast
    float key = 2.f * (pi.x * pj.x + pi.y * pj.y + pi.z * pj.z) - pj.w;
    topk_insert(t, pack_key(key, j));
  }
  if (h == 1) {
#pragma unroll
    for (int k = 0; k < K_; ++k) lists[q][k] = t[k];
  }
  __syncthreads();
  if (h == 0) {
    int* op = idx + ((size_t)b * P_ + r) * K_;
#pragma unroll
    for (int k = 0; k < K_; ++k) {
      unsigned long long o = lists[q][K_ - 1 - k];
      unsigned long long m = t[k] > o ? t[k] : o;   // bitonic top-K merge
      op[k] = (int)(~(unsigned)m);
    }
  }
}

// ---------------- Kernel 2: bv1[i][c] = pos_i @ W1[3:6] ----------------
__global__ __launch_bounds__(256) void bv1_kernel(
    const float* __restrict__ pos, const float* __restrict__ W1,
    float* __restrict__ bv) {
  int t = blockIdx.x * 256 + threadIdx.x;  // over B*P*64
  int c = t & 63, i = t >> 6;
  const float* p = pos + (size_t)i * 3;
  bv[t] = p[0] * W1[3 * 64 + c] + p[1] * W1[4 * 64 + c] + p[2] * W1[5 * 64 + c];
}

// ---------------- Kernel 3: layer-1 edge MLP + max over K -> x1, d2 -----
__global__ __launch_bounds__(256) void layer1_kernel(
    const float* __restrict__ pos, const float* __restrict__ W1,
    const float* __restrict__ b1, const float* __restrict__ g1,
    const float* __restrict__ bt1, const float* __restrict__ W2,
    const float* __restrict__ b2, const int* __restrict__ idx,
    const float* __restrict__ bv, float* __restrict__ x1,
    float* __restrict__ d2out) {
  __shared__ __align__(16) float W2t[64 * 68];  // W2t[n][c] = W2[c][n]
  __shared__ __align__(16) float T[4][K_ * 64];
  int b = blockIdx.y;
  int lane = threadIdx.x & 63;
  int w = threadIdx.x >> 6;
  for (int t = threadIdx.x; t < 64 * 64; t += 256) {
    int c = t >> 6, n = t & 63;
    W2t[n * 68 + c] = W2[c * 64 + n];
  }
  int i = blockIdx.x * 4 + w;
  size_t ip = (size_t)b * P_ + i;
  const float* posi = pos + ip * 3;
  float px = posi[0], py = posi[1], pz = posi[2];
  int c = lane;
  float cv = px * (W1[0 * 64 + c] - W1[3 * 64 + c]) +
             py * (W1[1 * 64 + c] - W1[4 * 64 + c]) +
             pz * (W1[2 * 64 + c] - W1[5 * 64 + c]) + b1[c];
  float g = g1[c], bt = bt1[c];
  const int* ji = idx + ip * K_;
  const float* bvb = bv + (size_t)b * P_ * 64;
  for (int k = 0; k < K_; ++k) {
    int j = ji[k];
    float t = cv + bvb[(size_t)j * 64 + c];
    t = fmaxf(t * g + bt, 0.f);
    T[w][k * 64 + c] = t;
  }
  __syncthreads();
  float acc[K_];
#pragma unroll
  for (int k = 0; k < K_; ++k) acc[k] = 0.f;
  const float4* Trow = (const float4*)&T[w][0];
#pragma unroll
  for (int c4 = 0; c4 < 16; ++c4) {
    float4 wv = *(const float4*)&W2t[lane * 68 + c4 * 4];
#pragma unroll
    for (int k = 0; k < K_; ++k) {
      float4 tvv = Trow[k * 16 + c4];  // broadcast
      acc[k] += tvv.x * wv.x + tvv.y * wv.y + tvv.z * wv.z + tvv.w * wv.w;
    }
  }
  float m = -INFINITY;
#pragma unroll
  for (int k = 0; k < K_; ++k) m = fmaxf(m, acc[k]);
  m += b2[lane];
  x1[ip * 64 + lane] = m;
  float s = m * m;
#pragma unroll
  for (int off = 32; off; off >>= 1) s += __shfl_xor(s, off, 64);
  if (lane == 0) d2out[ip] = s;
}

// ---------------- Kernel 4: kNN on 64-D x1 -> idx2 ----------------------
// grid (P/128, B), block 512 (8 waves). Per tile of 128 cols:
//   GEMM phase: 4x8 register microtile -> Cs[row][col] keys (stride 128).
//   Select phase: wave w owns rows w*16..w*16+15; per row, 64 lanes read 64
//   consecutive keys; ballot vs tau (=20th best, lane 0); serial loop over
//   qualifying bits with O(1) wave-distributed insert (list across lanes,
//   lane k = k-th smallest of top-20, lanes >=20 = UINT64_MAX sentinel).
__global__ __launch_bounds__(512) void knn64_kernel(
    const float* __restrict__ x1, const float* __restrict__ d2g,
    int* __restrict__ idx) {
  __shared__ __align__(16) float As[128 * 68];   // 34,816 B
  __shared__ __align__(16) float Bs[128 * 68];   // 34,816 B
  __shared__ __align__(16) float Cs[128 * 128];  // 65,536 B
  __shared__ float d2s[128];
  int b = blockIdx.y;
  int r0 = blockIdx.x * 128;
  const float* xb = x1 + (size_t)b * P_ * 64;
  int tid = threadIdx.x;
  int tr = tid >> 4;   // 0..31 -> rows tr*4+a
  int tc = tid & 15;   // cols tc+16*c
  int wv = tid >> 6;   // wave 0..7 -> select rows wv*16..+15
  int lane = tid & 63;

  // stage A (rows r0..r0+127): 2048 float4 / 512 thr = 4 each
  for (int g = tid; g < 128 * 16; g += 512) {
    int r = g >> 4, c4 = g & 15;
    *(float4*)(&As[r * 68 + c4 * 4]) =
        *(const float4*)(xb + (size_t)(r0 + r) * 64 + c4 * 4);
  }

  unsigned long long t[16];  // per-lane slice of 16 rows' top-20 lists
  unsigned long long seed = (lane < K_) ? 0ULL : ~0ULL;
#pragma unroll
  for (int rr = 0; rr < 16; ++rr) t[rr] = seed;

#pragma unroll 1
  for (int tile = 0; tile < 16; ++tile) {
    int j0 = tile * 128;
    __syncthreads();  // select(tile-1) done; safe to overwrite Bs/Cs
    for (int g = tid; g < 128 * 16; g += 512) {
      int r = g >> 4, c4 = g & 15;
      *(float4*)(&Bs[r * 68 + c4 * 4]) =
          *(const float4*)(xb + (size_t)(j0 + r) * 64 + c4 * 4);
    }
    if (tid < 128) d2s[tid] = d2g[(size_t)b * P_ + j0 + tid];
    __syncthreads();  // A,B,d2 staged

    // ---- GEMM: 4 rows x 8 cols per thread ----
    float acc[4][8];
#pragma unroll
    for (int a = 0; a < 4; ++a)
#pragma unroll
      for (int c = 0; c < 8; ++c) acc[a][c] = 0.f;
#pragma unroll
    for (int c4 = 0; c4 < 16; ++c4) {
      float4 af[4], bf[8];
#pragma unroll
      for (int a = 0; a < 4; ++a)
        af[a] = *(const float4*)(&As[(tr * 4 + a) * 68 + c4 * 4]);
#pragma unroll
      for (int c = 0; c < 8; ++c)
        bf[c] = *(const float4*)(&Bs[(tc + 16 * c) * 68 + c4 * 4]);
#pragma unroll
      for (int a = 0; a < 4; ++a)
#pragma unroll
        for (int c = 0; c < 8; ++c) {
          float s = acc[a][c];
          s = fmaf(af[a].x, bf[c].x, s);
          s = fmaf(af[a].y, bf[c].y, s);
          s = fmaf(af[a].z, bf[c].z, s);
          s = fmaf(af[a].w, bf[c].w, s);
          acc[a][c] = s;
        }
    }
#pragma unroll
    for (int a = 0; a < 4; ++a)
#pragma unroll
      for (int c = 0; c < 8; ++c) {
        int col = tc + 16 * c;
        Cs[(tr * 4 + a) * 128 + col] = 2.f * acc[a][c] - d2s[col];
      }
    __syncthreads();  // C tile ready

    // ---- Select: 16 rows per wave, 2 chunks of 64 per row ----
#pragma unroll
    for (int rr = 0; rr < 16; ++rr) {
      int row = wv * 16 + rr;
#pragma unroll
      for (int ch = 0; ch < 2; ++ch) {
        float key = Cs[row * 128 + ch * 64 + lane];
        unsigned long long x = pack_key(key, j0 + ch * 64 + lane);
        unsigned long long tau = __shfl(t[rr], 0, 64);  // 20th best
        unsigned long long mask = __ballot(x > tau);
        while (mask) {
          int src = __builtin_ctzll(mask);
          mask &= mask - 1;
          unsigned long long xi = __shfl(x, src, 64);
          unsigned long long up = __shfl_down(t[rr], 1, 64);  // lane63 -> own
          bool c2 = up < xi;
          bool c1 = t[rr] < xi;
          unsigned long long v = c1 ? xi : t[rr];
          t[rr] = c2 ? up : v;  // self-guarding insert
        }
      }
    }
  }

  // ---- Output (unsorted set is fine: consumers max-pool over K) ----
  if (lane < K_) {
#pragma unroll
    for (int rr = 0; rr < 16; ++rr) {
      int row = wv * 16 + rr;
      idx[((size_t)b * P_ + r0 + row) * K_ + lane] = (int)(~(unsigned)t[rr]);
    }
  }
}

// ---------------- Kernel 5: e2 = x1@(W3a-W3b)+b3, bb2 = x1@W3b ----------
__global__ __launch_bounds__(256) void ebb_kernel(
    const float* __restrict__ x1, const float* __restrict__ W3,
    const float* __restrict__ b3, float* __restrict__ e2,
    float* __restrict__ bb2) {
  __shared__ float xs[16 * 64];
  size_t p0 = (size_t)blockIdx.x * 16;
  for (int v = threadIdx.x; v < 16 * 64; v += 256) xs[v] = x1[p0 * 64 + v];
  __syncthreads();
  int n = threadIdx.x & 127;
  int which = threadIdx.x >> 7;  // wave-uniform
  float acc[16];
#pragma unroll
  for (int p = 0; p < 16; ++p) acc[p] = 0.f;
  for (int c = 0; c < 64; ++c) {
    float wa = W3[c * 128 + n];
    float wb = W3[(64 + c) * 128 + n];
    float wv = which ? wb : (wa - wb);
#pragma unroll
    for (int p = 0; p < 16; ++p) acc[p] += xs[p * 64 + c] * wv;
  }
  float bias = which ? 0.f : b3[n];
  float* dst = which ? bb2 : e2;
#pragma unroll
  for (int p = 0; p < 16; ++p) dst[(p0 + p) * 128 + n] = acc[p] + bias;
}

// ---------------- Kernel 6: x2 gather-max + hp@Wl + per-tile max --------
__global__ __launch_bounds__(256) void final_kernel(
    const float* __restrict__ x1, const float* __restrict__ e2,
    const float* __restrict__ bb2, const int* __restrict__ idx,
    const float* __restrict__ Wl, const float* __restrict__ bl,
    float* __restrict__ partial) {
  __shared__ float hp[32][192];
  __shared__ float smax[2][128];
  int b = blockIdx.y;
  int i0 = blockIdx.x * 32;
  size_t gp0 = (size_t)b * P_ + i0;
  for (int v = threadIdx.x; v < 32 * 64; v += 256) {
    int p = v >> 6, c = v & 63;
    hp[p][c] = x1[(gp0 + p) * 64 + c];
  }
  for (int v = threadIdx.x; v < 32 * 128; v += 256) {
    int p = v >> 7, n = v & 127;
    size_t gp = gp0 + p;
    const int* ji = idx + gp * K_;
    float m = -INFINITY;
    for (int k = 0; k < K_; ++k) {
      int j = ji[k];
      m = fmaxf(m, bb2[((size_t)b * P_ + j) * 128 + n]);
    }
    hp[p][64 + n] = e2[gp * 128 + n] + m;
  }
  __syncthreads();
  int n = threadIdx.x & 127;
  int pg = threadIdx.x >> 7;
  float acc[16];
#pragma unroll
  for (int p = 0; p < 16; ++p) acc[p] = 0.f;
  for (int c = 0; c < 192; ++c) {
    float wv = Wl[c * 128 + n];
#pragma unroll
    for (int p = 0; p < 16; ++p) acc[p] += hp[pg * 16 + p][c] * wv;
  }
  float m = -INFINITY;
#pragma unroll
  for (int p = 0; p < 16; ++p) m = fmaxf(m, acc[p]);
  smax[pg][n] = m;
  __syncthreads();
  if (threadIdx.x < 128) {
    float v = fmaxf(smax[0][n], smax[1][n]) + bl[n];
    partial[((size_t)b * 64 + blockIdx.x) * 128 + n] = v;
  }
}

// ---------------- Kernel 7: reduce partial maxes -> out (B,128) ---------
__global__ __launch_bounds__(256) void reduce_kernel(
    const float* __restrict__ partial, float* __restrict__ out) {
  int t = blockIdx.x * 256 + threadIdx.x;  // 4096
  int b = t >> 7, n = t & 127;
  float m = -INFINITY;
  for (int tb = 0; tb < 64; ++tb)
    m = fmaxf(m, partial[((size_t)b * 64 + tb) * 128 + n]);
  out[t] = m;
}

extern "C" void kernel_launch(void* const* d_in, const int* in_sizes, int n_in,
                              void* d_out, int out_size, void* d_ws,
                              size_t ws_size, hipStream_t stream) {
  (void)in_sizes; (void)n_in; (void)out_size; (void)ws_size;
  const float* pos = (const float*)d_in[0];
  const float* W1  = (const float*)d_in[1];
  const float* b1  = (const float*)d_in[2];
  const float* g1  = (const float*)d_in[3];
  const float* bt1 = (const float*)d_in[4];
  const float* W2  = (const float*)d_in[5];
  const float* b2  = (const float*)d_in[6];
  const float* W3  = (const float*)d_in[7];
  const float* b3  = (const float*)d_in[8];
  const float* Wl  = (const float*)d_in[9];
  const float* bl  = (const float*)d_in[10];
  float* out = (float*)d_out;

  // Workspace layout (bytes). Peak ~86.3 MB.
  char* w = (char*)d_ws;
  int*   idxp  = (int*)(w + 0);             //  5,242,880  idx1 then idx2
  float* x1p   = (float*)(w + 5242880);     // 16,777,216
  float* bv1p  = (float*)(w + 22020096);    // 33,554,432 region: bv1 then bb2
  float* bb2p  = bv1p;
  float* d2p   = (float*)(w + 55574528);    //    262,144
  float* e2p   = (float*)(w + 55836672);    // 33,554,432
  float* partp = (float*)(w + 89391104);    //  1,048,576

  knn3_kernel<<<dim3(P_ / 128, B_), 256, 0, stream>>>(pos, idxp);
  bv1_kernel<<<dim3(B_ * P_ * 64 / 256), 256, 0, stream>>>(pos, W1, bv1p);
  layer1_kernel<<<dim3(P_ / 4, B_), 256, 0, stream>>>(
      pos, W1, b1, g1, bt1, W2, b2, idxp, bv1p, x1p, d2p);
  knn64_kernel<<<dim3(P_ / 128, B_), 512, 0, stream>>>(x1p, d2p, idxp);
  ebb_kernel<<<dim3(B_ * P_ / 16), 256, 0, stream>>>(x1p, W3, b3, e2p, bb2p);
  final_kernel<<<dim3(P_ / 32, B_), 256, 0, stream>>>(
      x1p, e2p, bb2p, idxp, Wl, bl, partp);
  reduce_kernel<<<dim3(16), 256, 0, stream>>>(partp, out);
}

// Round 5
// 1523.612 us; speedup vs baseline: 1.9043x; 1.2743x over previous
//
#include <hip/hip_runtime.h>

#define B_ 32
#define P_ 2048
#define K_ 20

// ---- order-preserving (key, idx) packing -------------------------------
// larger key wins; ties -> smaller idx wins (matches jax.lax.top_k).
__device__ inline unsigned long long pack_key(float key, int j) {
  unsigned u = __float_as_uint(key);
  unsigned m = ((unsigned)((int)u >> 31)) | 0x80000000u;
  u ^= m;  // monotone float->uint
  return ((unsigned long long)u << 32) | (unsigned)(~j);
}

// ---------------- Kernel 1: kNN on 3-D positions -> idx1 ----------------
// grid (P/32, B), block 256 (4 waves). Wave w owns rows w*8..w*8+7.
// Wave-distributed top-K: the row's top-20 lives across lanes (lane k =
// k-th smallest kept; lanes >=20 hold sentinel MAX). Per 64-candidate
// chunk: per-lane key (3 FMA), ballot vs tau (=20th best, lane 0), then a
// serial loop over qualifying bits with an O(1) shfl-shift insert.
__global__ __launch_bounds__(256) void knn3_kernel(
    const float* __restrict__ pos, int* __restrict__ idx) {
  __shared__ float4 pts[P_];  // 32 KB: x,y,z,d2
  int b = blockIdx.y;
  const float* bp = pos + (size_t)b * P_ * 3;
  for (int j = threadIdx.x; j < P_; j += 256) {
    float x = bp[j * 3 + 0], y = bp[j * 3 + 1], z = bp[j * 3 + 2];
    pts[j] = make_float4(x, y, z, x * x + y * y + z * z);
  }
  __syncthreads();
  int wv = threadIdx.x >> 6;
  int lane = threadIdx.x & 63;
  int row0 = blockIdx.x * 32 + wv * 8;
  float4 pi[8];
#pragma unroll
  for (int rr = 0; rr < 8; ++rr) pi[rr] = pts[row0 + rr];  // uniform reads
  unsigned long long t[8];
  unsigned long long seed = (lane < K_) ? 0ULL : ~0ULL;
#pragma unroll
  for (int rr = 0; rr < 8; ++rr) t[rr] = seed;
#pragma unroll 1
  for (int ch = 0; ch < 32; ++ch) {
    float4 pj = pts[ch * 64 + lane];  // conflict-free b128
#pragma unroll
    for (int rr = 0; rr < 8; ++rr) {
      float key =
          2.f * (pi[rr].x * pj.x + pi[rr].y * pj.y + pi[rr].z * pj.z) - pj.w;
      unsigned long long x = pack_key(key, ch * 64 + lane);
      unsigned long long tau = __shfl(t[rr], 0, 64);  // current 20th best
      unsigned long long mask = __ballot(x > tau);
      while (mask) {
        int src = __builtin_ctzll(mask);
        mask &= mask - 1;
        unsigned long long xi = __shfl(x, src, 64);
        unsigned long long up = __shfl_down(t[rr], 1, 64);
        bool c2 = up < xi;
        bool c1 = t[rr] < xi;
        unsigned long long v = c1 ? xi : t[rr];
        t[rr] = c2 ? up : v;  // self-guarding insert
      }
    }
  }
  if (lane < K_) {
#pragma unroll
    for (int rr = 0; rr < 8; ++rr)
      idx[((size_t)b * P_ + row0 + rr) * K_ + lane] = (int)(~(unsigned)t[rr]);
  }
}

// ---------------- Kernel 2: bv1[i][c] = pos_i @ W1[3:6] ----------------
__global__ __launch_bounds__(256) void bv1_kernel(
    const float* __restrict__ pos, const float* __restrict__ W1,
    float* __restrict__ bv) {
  int t = blockIdx.x * 256 + threadIdx.x;  // over B*P*64
  int c = t & 63, i = t >> 6;
  const float* p = pos + (size_t)i * 3;
  bv[t] = p[0] * W1[3 * 64 + c] + p[1] * W1[4 * 64 + c] + p[2] * W1[5 * 64 + c];
}

// ---------------- Kernel 3: layer-1 edge MLP + max over K -> x1, d2 -----
__global__ __launch_bounds__(256) void layer1_kernel(
    const float* __restrict__ pos, const float* __restrict__ W1,
    const float* __restrict__ b1, const float* __restrict__ g1,
    const float* __restrict__ bt1, const float* __restrict__ W2,
    const float* __restrict__ b2, const int* __restrict__ idx,
    const float* __restrict__ bv, float* __restrict__ x1,
    float* __restrict__ d2out) {
  __shared__ __align__(16) float W2t[64 * 68];  // W2t[n][c] = W2[c][n]
  __shared__ __align__(16) float T[4][K_ * 64];
  int b = blockIdx.y;
  int lane = threadIdx.x & 63;
  int w = threadIdx.x >> 6;
  for (int t = threadIdx.x; t < 64 * 64; t += 256) {
    int c = t >> 6, n = t & 63;
    W2t[n * 68 + c] = W2[c * 64 + n];
  }
  int i = blockIdx.x * 4 + w;
  size_t ip = (size_t)b * P_ + i;
  const float* posi = pos + ip * 3;
  float px = posi[0], py = posi[1], pz = posi[2];
  int c = lane;
  float cv = px * (W1[0 * 64 + c] - W1[3 * 64 + c]) +
             py * (W1[1 * 64 + c] - W1[4 * 64 + c]) +
             pz * (W1[2 * 64 + c] - W1[5 * 64 + c]) + b1[c];
  float g = g1[c], bt = bt1[c];
  const int* ji = idx + ip * K_;
  const float* bvb = bv + (size_t)b * P_ * 64;
  for (int k = 0; k < K_; ++k) {
    int j = ji[k];
    float t = cv + bvb[(size_t)j * 64 + c];
    t = fmaxf(t * g + bt, 0.f);
    T[w][k * 64 + c] = t;
  }
  __syncthreads();
  float acc[K_];
#pragma unroll
  for (int k = 0; k < K_; ++k) acc[k] = 0.f;
  const float4* Trow = (const float4*)&T[w][0];
#pragma unroll
  for (int c4 = 0; c4 < 16; ++c4) {
    float4 wv = *(const float4*)&W2t[lane * 68 + c4 * 4];
#pragma unroll
    for (int k = 0; k < K_; ++k) {
      float4 tvv = Trow[k * 16 + c4];  // broadcast
      acc[k] += tvv.x * wv.x + tvv.y * wv.y + tvv.z * wv.z + tvv.w * wv.w;
    }
  }
  float m = -INFINITY;
#pragma unroll
  for (int k = 0; k < K_; ++k) m = fmaxf(m, acc[k]);
  m += b2[lane];
  x1[ip * 64 + lane] = m;
  float s = m * m;
#pragma unroll
  for (int off = 32; off; off >>= 1) s += __shfl_xor(s, off, 64);
  if (lane == 0) d2out[ip] = s;
}

// ---------------- Kernel 4: kNN on 64-D x1 -> idx2 ----------------------
// grid (P/128, B), block 512 (8 waves). Per tile of 128 cols:
//   GEMM phase: 4x8 register microtile -> Cs[row][col] keys (stride 128).
//   Select phase: wave-distributed top-K (same scheme as knn3).
__global__ __launch_bounds__(512) void knn64_kernel(
    const float* __restrict__ x1, const float* __restrict__ d2g,
    int* __restrict__ idx) {
  __shared__ __align__(16) float As[128 * 68];   // 34,816 B
  __shared__ __align__(16) float Bs[128 * 68];   // 34,816 B
  __shared__ __align__(16) float Cs[128 * 128];  // 65,536 B
  __shared__ float d2s[128];
  int b = blockIdx.y;
  int r0 = blockIdx.x * 128;
  const float* xb = x1 + (size_t)b * P_ * 64;
  int tid = threadIdx.x;
  int tr = tid >> 4;   // 0..31 -> rows tr*4+a
  int tc = tid & 15;   // cols tc+16*c
  int wv = tid >> 6;   // wave 0..7 -> select rows wv*16..+15
  int lane = tid & 63;

  // stage A (rows r0..r0+127)
  for (int g = tid; g < 128 * 16; g += 512) {
    int r = g >> 4, c4 = g & 15;
    *(float4*)(&As[r * 68 + c4 * 4]) =
        *(const float4*)(xb + (size_t)(r0 + r) * 64 + c4 * 4);
  }

  unsigned long long t[16];  // per-lane slice of 16 rows' top-20 lists
  unsigned long long seed = (lane < K_) ? 0ULL : ~0ULL;
#pragma unroll
  for (int rr = 0; rr < 16; ++rr) t[rr] = seed;

#pragma unroll 1
  for (int tile = 0; tile < 16; ++tile) {
    int j0 = tile * 128;
    __syncthreads();  // select(tile-1) done; safe to overwrite Bs/Cs
    for (int g = tid; g < 128 * 16; g += 512) {
      int r = g >> 4, c4 = g & 15;
      *(float4*)(&Bs[r * 68 + c4 * 4]) =
          *(const float4*)(xb + (size_t)(j0 + r) * 64 + c4 * 4);
    }
    if (tid < 128) d2s[tid] = d2g[(size_t)b * P_ + j0 + tid];
    __syncthreads();  // A,B,d2 staged

    // ---- GEMM: 4 rows x 8 cols per thread ----
    float acc[4][8];
#pragma unroll
    for (int a = 0; a < 4; ++a)
#pragma unroll
      for (int c = 0; c < 8; ++c) acc[a][c] = 0.f;
#pragma unroll
    for (int c4 = 0; c4 < 16; ++c4) {
      float4 af[4], bf[8];
#pragma unroll
      for (int a = 0; a < 4; ++a)
        af[a] = *(const float4*)(&As[(tr * 4 + a) * 68 + c4 * 4]);
#pragma unroll
      for (int c = 0; c < 8; ++c)
        bf[c] = *(const float4*)(&Bs[(tc + 16 * c) * 68 + c4 * 4]);
#pragma unroll
      for (int a = 0; a < 4; ++a)
#pragma unroll
        for (int c = 0; c < 8; ++c) {
          float s = acc[a][c];
          s = fmaf(af[a].x, bf[c].x, s);
          s = fmaf(af[a].y, bf[c].y, s);
          s = fmaf(af[a].z, bf[c].z, s);
          s = fmaf(af[a].w, bf[c].w, s);
          acc[a][c] = s;
        }
    }
#pragma unroll
    for (int a = 0; a < 4; ++a)
#pragma unroll
      for (int c = 0; c < 8; ++c) {
        int col = tc + 16 * c;
        Cs[(tr * 4 + a) * 128 + col] = 2.f * acc[a][c] - d2s[col];
      }
    __syncthreads();  // C tile ready

    // ---- Select: 16 rows per wave, 2 chunks of 64 per row ----
#pragma unroll
    for (int rr = 0; rr < 16; ++rr) {
      int row = wv * 16 + rr;
#pragma unroll
      for (int ch = 0; ch < 2; ++ch) {
        float key = Cs[row * 128 + ch * 64 + lane];
        unsigned long long x = pack_key(key, j0 + ch * 64 + lane);
        unsigned long long tau = __shfl(t[rr], 0, 64);  // 20th best
        unsigned long long mask = __ballot(x > tau);
        while (mask) {
          int src = __builtin_ctzll(mask);
          mask &= mask - 1;
          unsigned long long xi = __shfl(x, src, 64);
          unsigned long long up = __shfl_down(t[rr], 1, 64);
          bool c2 = up < xi;
          bool c1 = t[rr] < xi;
          unsigned long long v = c1 ? xi : t[rr];
          t[rr] = c2 ? up : v;  // self-guarding insert
        }
      }
    }
  }

  // ---- Output (unsorted set is fine: consumers max-pool over K) ----
  if (lane < K_) {
#pragma unroll
    for (int rr = 0; rr < 16; ++rr) {
      int row = wv * 16 + rr;
      idx[((size_t)b * P_ + r0 + row) * K_ + lane] = (int)(~(unsigned)t[rr]);
    }
  }
}

// ---------------- Kernel 5: e2 = x1@(W3a-W3b)+b3, bb2 = x1@W3b ----------
__global__ __launch_bounds__(256) void ebb_kernel(
    const float* __restrict__ x1, const float* __restrict__ W3,
    const float* __restrict__ b3, float* __restrict__ e2,
    float* __restrict__ bb2) {
  __shared__ float xs[16 * 64];
  size_t p0 = (size_t)blockIdx.x * 16;
  for (int v = threadIdx.x; v < 16 * 64; v += 256) xs[v] = x1[p0 * 64 + v];
  __syncthreads();
  int n = threadIdx.x & 127;
  int which = threadIdx.x >> 7;  // wave-uniform
  float acc[16];
#pragma unroll
  for (int p = 0; p < 16; ++p) acc[p] = 0.f;
  for (int c = 0; c < 64; ++c) {
    float wa = W3[c * 128 + n];
    float wb = W3[(64 + c) * 128 + n];
    float wv = which ? wb : (wa - wb);
#pragma unroll
    for (int p = 0; p < 16; ++p) acc[p] += xs[p * 64 + c] * wv;
  }
  float bias = which ? 0.f : b3[n];
  float* dst = which ? bb2 : e2;
#pragma unroll
  for (int p = 0; p < 16; ++p) dst[(p0 + p) * 128 + n] = acc[p] + bias;
}

// ---------------- Kernel 6: x2 gather-max + hp@Wl + per-tile max --------
__global__ __launch_bounds__(256) void final_kernel(
    const float* __restrict__ x1, const float* __restrict__ e2,
    const float* __restrict__ bb2, const int* __restrict__ idx,
    const float* __restrict__ Wl, const float* __restrict__ bl,
    float* __restrict__ partial) {
  __shared__ float hp[32][192];
  __shared__ float smax[2][128];
  int b = blockIdx.y;
  int i0 = blockIdx.x * 32;
  size_t gp0 = (size_t)b * P_ + i0;
  for (int v = threadIdx.x; v < 32 * 64; v += 256) {
    int p = v >> 6, c = v & 63;
    hp[p][c] = x1[(gp0 + p) * 64 + c];
  }
  for (int v = threadIdx.x; v < 32 * 128; v += 256) {
    int p = v >> 7, n = v & 127;
    size_t gp = gp0 + p;
    const int* ji = idx + gp * K_;
    float m = -INFINITY;
    for (int k = 0; k < K_; ++k) {
      int j = ji[k];
      m = fmaxf(m, bb2[((size_t)b * P_ + j) * 128 + n]);
    }
    hp[p][64 + n] = e2[gp * 128 + n] + m;
  }
  __syncthreads();
  int n = threadIdx.x & 127;
  int pg = threadIdx.x >> 7;
  float acc[16];
#pragma unroll
  for (int p = 0; p < 16; ++p) acc[p] = 0.f;
  for (int c = 0; c < 192; ++c) {
    float wv = Wl[c * 128 + n];
#pragma unroll
    for (int p = 0; p < 16; ++p) acc[p] += hp[pg * 16 + p][c] * wv;
  }
  float m = -INFINITY;
#pragma unroll
  for (int p = 0; p < 16; ++p) m = fmaxf(m, acc[p]);
  smax[pg][n] = m;
  __syncthreads();
  if (threadIdx.x < 128) {
    float v = fmaxf(smax[0][n], smax[1][n]) + bl[n];
    partial[((size_t)b * 64 + blockIdx.x) * 128 + n] = v;
  }
}

// ---------------- Kernel 7: reduce partial maxes -> out (B,128) ---------
__global__ __launch_bounds__(256) void reduce_kernel(
    const float* __restrict__ partial, float* __restrict__ out) {
  int t = blockIdx.x * 256 + threadIdx.x;  // 4096
  int b = t >> 7, n = t & 127;
  float m = -INFINITY;
  for (int tb = 0; tb < 64; ++tb)
    m = fmaxf(m, partial[((size_t)b * 64 + tb) * 128 + n]);
  out[t] = m;
}

extern "C" void kernel_launch(void* const* d_in, const int* in_sizes, int n_in,
                              void* d_out, int out_size, void* d_ws,
                              size_t ws_size, hipStream_t stream) {
  (void)in_sizes; (void)n_in; (void)out_size; (void)ws_size;
  const float* pos = (const float*)d_in[0];
  const float* W1  = (const float*)d_in[1];
  const float* b1  = (const float*)d_in[2];
  const float* g1  = (const float*)d_in[3];
  const float* bt1 = (const float*)d_in[4];
  const float* W2  = (const float*)d_in[5];
  const float* b2  = (const float*)d_in[6];
  const float* W3  = (const float*)d_in[7];
  const float* b3  = (const float*)d_in[8];
  const float* Wl  = (const float*)d_in[9];
  const float* bl  = (const float*)d_in[10];
  float* out = (float*)d_out;

  // Workspace layout (bytes). Peak ~86.3 MB.
  char* w = (char*)d_ws;
  int*   idxp  = (int*)(w + 0);             //  5,242,880  idx1 then idx2
  float* x1p   = (float*)(w + 5242880);     // 16,777,216
  float* bv1p  = (float*)(w + 22020096);    // 33,554,432 region: bv1 then bb2
  float* bb2p  = bv1p;
  float* d2p   = (float*)(w + 55574528);    //    262,144
  float* e2p   = (float*)(w + 55836672);    // 33,554,432
  float* partp = (float*)(w + 89391104);    //  1,048,576

  knn3_kernel<<<dim3(P_ / 32, B_), 256, 0, stream>>>(pos, idxp);
  bv1_kernel<<<dim3(B_ * P_ * 64 / 256), 256, 0, stream>>>(pos, W1, bv1p);
  layer1_kernel<<<dim3(P_ / 4, B_), 256, 0, stream>>>(
      pos, W1, b1, g1, bt1, W2, b2, idxp, bv1p, x1p, d2p);
  knn64_kernel<<<dim3(P_ / 128, B_), 512, 0, stream>>>(x1p, d2p, idxp);
  ebb_kernel<<<dim3(B_ * P_ / 16), 256, 0, stream>>>(x1p, W3, b3, e2p, bb2p);
  final_kernel<<<dim3(P_ / 32, B_), 256, 0, stream>>>(
      x1p, e2p, bb2p, idxp, Wl, bl, partp);
  reduce_kernel<<<dim3(16), 256, 0, stream>>>(partp, out);
}

// Round 6
// 1342.700 us; speedup vs baseline: 2.1608x; 1.1347x over previous
//
#include <hip/hip_runtime.h>

#define B_ 32
#define P_ 2048
#define K_ 20

// ---- order-preserving (key, idx) packing -------------------------------
// larger key wins; ties -> smaller idx wins (matches jax.lax.top_k).
__device__ inline unsigned monok(float key) {
  unsigned u = __float_as_uint(key);
  return u ^ (((unsigned)((int)u >> 31)) | 0x80000000u);  // monotone f32->u32
}
__device__ inline unsigned long long pack_key(float key, int j) {
  return ((unsigned long long)monok(key) << 32) | (unsigned)(~j);
}

// u64 readlane (wave-uniform lane) -> scalar
__device__ inline unsigned long long rl64(unsigned long long v, int lane) {
  unsigned lo = (unsigned)__builtin_amdgcn_readlane((int)(unsigned)v, lane);
  unsigned hi = (unsigned)__builtin_amdgcn_readlane((int)(unsigned)(v >> 32), lane);
  return ((unsigned long long)hi << 32) | lo;
}

// Wave-distributed top-K insert loop. List lives across lanes: lane k =
// k-th smallest kept (lane 0 = 20th best = tau), lanes >= K_ = ~0 sentinel.
// mask = ballot of candidates x (per-lane) exceeding stale tau; xi broadcast
// via readlane (no DS), stale candidates skipped by scalar branch; only the
// list shift uses shfl_down (2 ds_bpermute).
__device__ inline void topk_drain(unsigned long long& t, unsigned long long x,
                                  unsigned long long mask) {
  while (mask) {
    int src = __builtin_ctzll(mask);
    mask &= mask - 1;
    unsigned long long xi = rl64(x, src);
    unsigned long long tau = rl64(t, 0);
    if (xi <= tau) continue;  // stale (uniform branch)
    unsigned long long up = __shfl_down(t, 1, 64);
    bool c1 = t < xi;
    bool c2 = up < xi;
    unsigned long long v = c1 ? xi : t;
    t = c2 ? up : v;
  }
}

// ---------------- Kernel 1: kNN on 3-D positions -> idx1 ----------------
// grid (P/32, B), block 256 (4 waves). Wave w owns rows w*8..w*8+7.
__global__ __launch_bounds__(256) void knn3_kernel(
    const float* __restrict__ pos, int* __restrict__ idx) {
  __shared__ float4 pts[P_];  // 32 KB: x,y,z,d2
  int b = blockIdx.y;
  const float* bp = pos + (size_t)b * P_ * 3;
  for (int j = threadIdx.x; j < P_; j += 256) {
    float x = bp[j * 3 + 0], y = bp[j * 3 + 1], z = bp[j * 3 + 2];
    pts[j] = make_float4(x, y, z, x * x + y * y + z * z);
  }
  __syncthreads();
  int wv = threadIdx.x >> 6;
  int lane = threadIdx.x & 63;
  int row0 = blockIdx.x * 32 + wv * 8;
  float4 pi[8];
#pragma unroll
  for (int rr = 0; rr < 8; ++rr) pi[rr] = pts[row0 + rr];  // uniform reads
  unsigned long long t[8];
  unsigned long long seed = (lane < K_) ? 0ULL : ~0ULL;
#pragma unroll
  for (int rr = 0; rr < 8; ++rr) t[rr] = seed;
#pragma unroll 1
  for (int ch = 0; ch < 32; ++ch) {
    float4 pj = pts[ch * 64 + lane];  // conflict-free b128
#pragma unroll
    for (int rr = 0; rr < 8; ++rr) {
      float key =
          2.f * (pi[rr].x * pj.x + pi[rr].y * pj.y + pi[rr].z * pj.z) - pj.w;
      unsigned long long x = pack_key(key, ch * 64 + lane);
      unsigned long long tau = rl64(t[rr], 0);
      unsigned long long mask = __ballot(x > tau);
      topk_drain(t[rr], x, mask);
    }
  }
  if (lane < K_) {
#pragma unroll
    for (int rr = 0; rr < 8; ++rr)
      idx[((size_t)b * P_ + row0 + rr) * K_ + lane] = (int)(~(unsigned)t[rr]);
  }
}

// ---------------- Kernel 2: bv1[i][c] = pos_i @ W1[3:6] ----------------
__global__ __launch_bounds__(256) void bv1_kernel(
    const float* __restrict__ pos, const float* __restrict__ W1,
    float* __restrict__ bv) {
  int t = blockIdx.x * 256 + threadIdx.x;  // over B*P*64
  int c = t & 63, i = t >> 6;
  const float* p = pos + (size_t)i * 3;
  bv[t] = p[0] * W1[3 * 64 + c] + p[1] * W1[4 * 64 + c] + p[2] * W1[5 * 64 + c];
}

// ---------------- Kernel 3: layer-1 edge MLP + max over K -> x1, d2 -----
__global__ __launch_bounds__(256) void layer1_kernel(
    const float* __restrict__ pos, const float* __restrict__ W1,
    const float* __restrict__ b1, const float* __restrict__ g1,
    const float* __restrict__ bt1, const float* __restrict__ W2,
    const float* __restrict__ b2, const int* __restrict__ idx,
    const float* __restrict__ bv, float* __restrict__ x1,
    float* __restrict__ d2out) {
  __shared__ __align__(16) float W2t[64 * 68];  // W2t[n][c] = W2[c][n]
  __shared__ __align__(16) float T[4][K_ * 64];
  int b = blockIdx.y;
  int lane = threadIdx.x & 63;
  int w = threadIdx.x >> 6;
  for (int t = threadIdx.x; t < 64 * 64; t += 256) {
    int c = t >> 6, n = t & 63;
    W2t[n * 68 + c] = W2[c * 64 + n];
  }
  int i = blockIdx.x * 4 + w;
  size_t ip = (size_t)b * P_ + i;
  const float* posi = pos + ip * 3;
  float px = posi[0], py = posi[1], pz = posi[2];
  int c = lane;
  float cv = px * (W1[0 * 64 + c] - W1[3 * 64 + c]) +
             py * (W1[1 * 64 + c] - W1[4 * 64 + c]) +
             pz * (W1[2 * 64 + c] - W1[5 * 64 + c]) + b1[c];
  float g = g1[c], bt = bt1[c];
  const int* ji = idx + ip * K_;
  const float* bvb = bv + (size_t)b * P_ * 64;
  for (int k = 0; k < K_; ++k) {
    int j = ji[k];
    float t = cv + bvb[(size_t)j * 64 + c];
    t = fmaxf(t * g + bt, 0.f);
    T[w][k * 64 + c] = t;
  }
  __syncthreads();
  float acc[K_];
#pragma unroll
  for (int k = 0; k < K_; ++k) acc[k] = 0.f;
  const float4* Trow = (const float4*)&T[w][0];
#pragma unroll
  for (int c4 = 0; c4 < 16; ++c4) {
    float4 wv = *(const float4*)&W2t[lane * 68 + c4 * 4];
#pragma unroll
    for (int k = 0; k < K_; ++k) {
      float4 tvv = Trow[k * 16 + c4];  // broadcast
      acc[k] += tvv.x * wv.x + tvv.y * wv.y + tvv.z * wv.z + tvv.w * wv.w;
    }
  }
  float m = -INFINITY;
#pragma unroll
  for (int k = 0; k < K_; ++k) m = fmaxf(m, acc[k]);
  m += b2[lane];
  x1[ip * 64 + lane] = m;
  float s = m * m;
#pragma unroll
  for (int off = 32; off; off >>= 1) s += __shfl_xor(s, off, 64);
  if (lane == 0) d2out[ip] = s;
}

// ---------------- Kernel 4a: Gram scores -> packed u32 keys (global) ----
// grid (32 row-panels, 2 col-halves, chunkB), block 256.
// Per block: 64 rows x 1024 cols of one batch; 8 col-tiles of 128.
// key[r][c] = monok(2*dot(x_r,x_c) - d2_c); identical fp32 math to round 5.
__global__ __launch_bounds__(256) void gemm_scores_kernel(
    const float* __restrict__ x1, const float* __restrict__ d2g,
    unsigned* __restrict__ scores, int chunkBase) {
  __shared__ __align__(16) float As[64 * 68];    // 17,408 B
  __shared__ __align__(16) float Bs[128 * 68];   // 34,816 B
  __shared__ float d2s[128];
  int bz = blockIdx.z;
  int b = chunkBase + bz;
  int r0 = blockIdx.x * 64;
  int c0 = blockIdx.y * 1024;
  const float* xb = x1 + (size_t)b * P_ * 64;
  unsigned* sb = scores + ((size_t)bz * P_ + r0) * P_;
  int tid = threadIdx.x;
  int tr = tid >> 4;  // 0..15 -> rows tr*4+a
  int tc = tid & 15;  // cols tc+16*c

  for (int g = tid; g < 64 * 16; g += 256) {
    int r = g >> 4, c4 = g & 15;
    *(float4*)&As[r * 68 + c4 * 4] =
        *(const float4*)(xb + (size_t)(r0 + r) * 64 + c4 * 4);
  }

#pragma unroll 1
  for (int tile = 0; tile < 8; ++tile) {
    int j0 = c0 + tile * 128;
    __syncthreads();  // previous tile's Bs reads done
    for (int g = tid; g < 128 * 16; g += 256) {
      int r = g >> 4, c4 = g & 15;
      *(float4*)&Bs[r * 68 + c4 * 4] =
          *(const float4*)(xb + (size_t)(j0 + r) * 64 + c4 * 4);
    }
    if (tid < 128) d2s[tid] = d2g[(size_t)b * P_ + j0 + tid];
    __syncthreads();

    float acc[4][8];
#pragma unroll
    for (int a = 0; a < 4; ++a)
#pragma unroll
      for (int c = 0; c < 8; ++c) acc[a][c] = 0.f;
#pragma unroll
    for (int c4 = 0; c4 < 16; ++c4) {
      float4 af[4], bf[8];
#pragma unroll
      for (int a = 0; a < 4; ++a)
        af[a] = *(const float4*)(&As[(tr * 4 + a) * 68 + c4 * 4]);
#pragma unroll
      for (int c = 0; c < 8; ++c)
        bf[c] = *(const float4*)(&Bs[(tc + 16 * c) * 68 + c4 * 4]);
#pragma unroll
      for (int a = 0; a < 4; ++a)
#pragma unroll
        for (int c = 0; c < 8; ++c) {
          float s = acc[a][c];
          s = fmaf(af[a].x, bf[c].x, s);
          s = fmaf(af[a].y, bf[c].y, s);
          s = fmaf(af[a].z, bf[c].z, s);
          s = fmaf(af[a].w, bf[c].w, s);
          acc[a][c] = s;
        }
    }
    // epilogue: per instr, 16 lanes cover 16 consecutive cols (64B) x 4 rows
#pragma unroll
    for (int a = 0; a < 4; ++a)
#pragma unroll
      for (int c = 0; c < 8; ++c) {
        int col = tc + 16 * c;
        sb[(size_t)(tr * 4 + a) * P_ + j0 + col] =
            monok(2.f * acc[a][c] - d2s[col]);
      }
  }
}

// ---------------- Kernel 4b: select top-20 per row from key buffer ------
// grid (P/4, chunkB), block 256: one wave per row, no LDS.
__global__ __launch_bounds__(256) void knn_select_kernel(
    const unsigned* __restrict__ scores, int* __restrict__ idx,
    int chunkBase) {
  int bb = blockIdx.y;
  int b = chunkBase + bb;
  int row = blockIdx.x * 4 + (threadIdx.x >> 6);
  int lane = threadIdx.x & 63;
  const unsigned* sp = scores + ((size_t)bb * P_ + row) * P_;
  unsigned long long t = (lane < K_) ? 0ULL : ~0ULL;
#pragma unroll 1
  for (int it = 0; it < P_ / 256; ++it) {
    uint4 kv = *(const uint4*)(sp + it * 256 + lane * 4);
    int cb = it * 256 + lane * 4;
#pragma unroll
    for (int q = 0; q < 4; ++q) {
      unsigned key = q == 0 ? kv.x : q == 1 ? kv.y : q == 2 ? kv.z : kv.w;
      unsigned long long x =
          ((unsigned long long)key << 32) | (unsigned)(~(cb + q));
      unsigned long long tau = rl64(t, 0);
      unsigned long long mask = __ballot(x > tau);
      topk_drain(t, x, mask);
    }
  }
  if (lane < K_)
    idx[((size_t)b * P_ + row) * K_ + lane] = (int)(~(unsigned)t);
}

// ---------------- Kernel 5: e2 = x1@(W3a-W3b)+b3, bb2 = x1@W3b ----------
__global__ __launch_bounds__(256) void ebb_kernel(
    const float* __restrict__ x1, const float* __restrict__ W3,
    const float* __restrict__ b3, float* __restrict__ e2,
    float* __restrict__ bb2) {
  __shared__ float xs[16 * 64];
  size_t p0 = (size_t)blockIdx.x * 16;
  for (int v = threadIdx.x; v < 16 * 64; v += 256) xs[v] = x1[p0 * 64 + v];
  __syncthreads();
  int n = threadIdx.x & 127;
  int which = threadIdx.x >> 7;  // wave-uniform
  float acc[16];
#pragma unroll
  for (int p = 0; p < 16; ++p) acc[p] = 0.f;
  for (int c = 0; c < 64; ++c) {
    float wa = W3[c * 128 + n];
    float wb = W3[(64 + c) * 128 + n];
    float wv = which ? wb : (wa - wb);
#pragma unroll
    for (int p = 0; p < 16; ++p) acc[p] += xs[p * 64 + c] * wv;
  }
  float bias = which ? 0.f : b3[n];
  float* dst = which ? bb2 : e2;
#pragma unroll
  for (int p = 0; p < 16; ++p) dst[(p0 + p) * 128 + n] = acc[p] + bias;
}

// ---------------- Kernel 6: x2 gather-max + hp@Wl + per-tile max --------
__global__ __launch_bounds__(256) void final_kernel(
    const float* __restrict__ x1, const float* __restrict__ e2,
    const float* __restrict__ bb2, const int* __restrict__ idx,
    const float* __restrict__ Wl, const float* __restrict__ bl,
    float* __restrict__ partial) {
  __shared__ float hp[32][192];
  __shared__ float smax[2][128];
  int b = blockIdx.y;
  int i0 = blockIdx.x * 32;
  size_t gp0 = (size_t)b * P_ + i0;
  for (int v = threadIdx.x; v < 32 * 64; v += 256) {
    int p = v >> 6, c = v & 63;
    hp[p][c] = x1[(gp0 + p) * 64 + c];
  }
  for (int v = threadIdx.x; v < 32 * 128; v += 256) {
    int p = v >> 7, n = v & 127;
    size_t gp = gp0 + p;
    const int* ji = idx + gp * K_;
    float m = -INFINITY;
    for (int k = 0; k < K_; ++k) {
      int j = ji[k];
      m = fmaxf(m, bb2[((size_t)b * P_ + j) * 128 + n]);
    }
    hp[p][64 + n] = e2[gp * 128 + n] + m;
  }
  __syncthreads();
  int n = threadIdx.x & 127;
  int pg = threadIdx.x >> 7;
  float acc[16];
#pragma unroll
  for (int p = 0; p < 16; ++p) acc[p] = 0.f;
  for (int c = 0; c < 192; ++c) {
    float wv = Wl[c * 128 + n];
#pragma unroll
    for (int p = 0; p < 16; ++p) acc[p] += hp[pg * 16 + p][c] * wv;
  }
  float m = -INFINITY;
#pragma unroll
  for (int p = 0; p < 16; ++p) m = fmaxf(m, acc[p]);
  smax[pg][n] = m;
  __syncthreads();
  if (threadIdx.x < 128) {
    float v = fmaxf(smax[0][n], smax[1][n]) + bl[n];
    partial[((size_t)b * 64 + blockIdx.x) * 128 + n] = v;
  }
}

// ---------------- Kernel 7: reduce partial maxes -> out (B,128) ---------
__global__ __launch_bounds__(256) void reduce_kernel(
    const float* __restrict__ partial, float* __restrict__ out) {
  int t = blockIdx.x * 256 + threadIdx.x;  // 4096
  int b = t >> 7, n = t & 127;
  float m = -INFINITY;
  for (int tb = 0; tb < 64; ++tb)
    m = fmaxf(m, partial[((size_t)b * 64 + tb) * 128 + n]);
  out[t] = m;
}

extern "C" void kernel_launch(void* const* d_in, const int* in_sizes, int n_in,
                              void* d_out, int out_size, void* d_ws,
                              size_t ws_size, hipStream_t stream) {
  (void)in_sizes; (void)n_in; (void)out_size;
  const float* pos = (const float*)d_in[0];
  const float* W1  = (const float*)d_in[1];
  const float* b1  = (const float*)d_in[2];
  const float* g1  = (const float*)d_in[3];
  const float* bt1 = (const float*)d_in[4];
  const float* W2  = (const float*)d_in[5];
  const float* b2  = (const float*)d_in[6];
  const float* W3  = (const float*)d_in[7];
  const float* b3  = (const float*)d_in[8];
  const float* Wl  = (const float*)d_in[9];
  const float* bl  = (const float*)d_in[10];
  float* out = (float*)d_out;

  // Workspace layout (bytes), peak 90,439,680 (same as prior rounds):
  //   [0, 5242880)          idx (idx1 then idx2)
  //   [5242880, 22020096)   x1
  //   [22020096, 22282240)  d2
  //   [22282240, 23330816)  partial
  //   [23330816, 90439680)  region (67,108,864): bv1 -> scores -> e2|bb2
  char* w = (char*)d_ws;
  int*      idxp  = (int*)(w + 0);
  float*    x1p   = (float*)(w + 5242880);
  float*    d2p   = (float*)(w + 22020096);
  float*    partp = (float*)(w + 22282240);
  float*    bv1p  = (float*)(w + 23330816);  // dead after layer1
  unsigned* scp   = (unsigned*)(w + 23330816);  // live only during kNN-2
  float*    e2p   = (float*)(w + 23330816);     // live after kNN-2
  float*    bb2p  = (float*)(w + 23330816 + 33554432);

  // Adaptive score-chunk: per batch 2048*2048*4 = 16,777,216 B.
  size_t avail = ws_size > 23330816 ? ws_size - 23330816 : 0;
  int chunkB = 4;  // guaranteed: region holds 4 x 16 MB
  if (avail >= (size_t)16 * 16777216) chunkB = 16;
  else if (avail >= (size_t)8 * 16777216) chunkB = 8;

  knn3_kernel<<<dim3(P_ / 32, B_), 256, 0, stream>>>(pos, idxp);
  bv1_kernel<<<dim3(B_ * P_ * 64 / 256), 256, 0, stream>>>(pos, W1, bv1p);
  layer1_kernel<<<dim3(P_ / 4, B_), 256, 0, stream>>>(
      pos, W1, b1, g1, bt1, W2, b2, idxp, bv1p, x1p, d2p);
  for (int cb = 0; cb < B_; cb += chunkB) {
    gemm_scores_kernel<<<dim3(32, 2, chunkB), 256, 0, stream>>>(
        x1p, d2p, scp, cb);
    knn_select_kernel<<<dim3(P_ / 4, chunkB), 256, 0, stream>>>(
        scp, idxp, cb);
  }
  ebb_kernel<<<dim3(B_ * P_ / 16), 256, 0, stream>>>(x1p, W3, b3, e2p, bb2p);
  final_kernel<<<dim3(P_ / 32, B_), 256, 0, stream>>>(
      x1p, e2p, bb2p, idxp, Wl, bl, partp);
  reduce_kernel<<<dim3(16), 256, 0, stream>>>(partp, out);
}

// Round 7
// 1099.138 us; speedup vs baseline: 2.6397x; 1.2216x over previous
//
#include <hip/hip_runtime.h>

#define B_ 32
#define P_ 2048
#define K_ 20

// ---- order-preserving (key, idx) packing -------------------------------
// larger key wins; ties -> smaller idx wins (matches jax.lax.top_k).
__device__ inline unsigned monok(float key) {
  unsigned u = __float_as_uint(key);
  return u ^ (((unsigned)((int)u >> 31)) | 0x80000000u);  // monotone f32->u32
}
__device__ inline unsigned long long pack_key(float key, int j) {
  return ((unsigned long long)monok(key) << 32) | (unsigned)(~j);
}

// u64 readlane (wave-uniform lane) -> scalar
__device__ inline unsigned long long rl64(unsigned long long v, int lane) {
  unsigned lo = (unsigned)__builtin_amdgcn_readlane((int)(unsigned)v, lane);
  unsigned hi = (unsigned)__builtin_amdgcn_readlane((int)(unsigned)(v >> 32), lane);
  return ((unsigned long long)hi << 32) | lo;
}

// Wave-distributed top-K insert loop. List lives across lanes: lane k =
// k-th smallest kept (lane 0 = 20th best = tau), lanes >= K_ = ~0 sentinel.
__device__ inline void topk_drain(unsigned long long& t, unsigned long long x,
                                  unsigned long long mask) {
  while (mask) {
    int src = __builtin_ctzll(mask);
    mask &= mask - 1;
    unsigned long long xi = rl64(x, src);
    unsigned long long tau = rl64(t, 0);
    if (xi <= tau) continue;  // stale (uniform branch)
    unsigned long long up = __shfl_down(t, 1, 64);
    bool c1 = t < xi;
    bool c2 = up < xi;
    unsigned long long v = c1 ? xi : t;
    t = c2 ? up : v;
  }
}

// Full ascending bitonic sort of 64 u64 across the wave's lanes.
__device__ inline unsigned long long sort64(unsigned long long v, int lane) {
#pragma unroll
  for (int k = 2; k <= 64; k <<= 1) {
#pragma unroll
    for (int j = k >> 1; j > 0; j >>= 1) {
      unsigned long long o = __shfl_xor(v, j, 64);
      bool keepMin = ((lane & j) == 0) == ((lane & k) == 0);
      unsigned long long mn = v < o ? v : o;
      unsigned long long mx = v < o ? o : v;
      v = keepMin ? mn : mx;
    }
  }
  return v;
}

// Seed the wave-distributed top-20 list from 64 candidates (1/lane):
// sort ascending, move top-20 (lanes 44..63) to lanes 0..19, sentinel rest.
__device__ inline unsigned long long topk_seed(unsigned long long x, int lane) {
  unsigned long long s = sort64(x, lane);
  unsigned long long v = __shfl(s, lane + 44, 64);
  return (lane < K_) ? v : ~0ULL;
}

// ---------------- Kernel 1: kNN on 3-D positions -> idx1 ----------------
// grid (P/32, B), block 256 (4 waves). Wave w owns rows w*8..w*8+7.
__global__ __launch_bounds__(256) void knn3_kernel(
    const float* __restrict__ pos, int* __restrict__ idx) {
  __shared__ float4 pts[P_];  // 32 KB: x,y,z,d2
  int b = blockIdx.y;
  const float* bp = pos + (size_t)b * P_ * 3;
  for (int j = threadIdx.x; j < P_; j += 256) {
    float x = bp[j * 3 + 0], y = bp[j * 3 + 1], z = bp[j * 3 + 2];
    pts[j] = make_float4(x, y, z, x * x + y * y + z * z);
  }
  __syncthreads();
  int wv = threadIdx.x >> 6;
  int lane = threadIdx.x & 63;
  int row0 = blockIdx.x * 32 + wv * 8;
  float4 pi[8];
#pragma unroll
  for (int rr = 0; rr < 8; ++rr) pi[rr] = pts[row0 + rr];  // uniform reads
  unsigned long long t[8];
  // chunk 0: bitonic sort-seed (replaces 64 serial drains per row)
  {
    float4 pj = pts[lane];
#pragma unroll
    for (int rr = 0; rr < 8; ++rr) {
      float key =
          2.f * (pi[rr].x * pj.x + pi[rr].y * pj.y + pi[rr].z * pj.z) - pj.w;
      t[rr] = topk_seed(pack_key(key, lane), lane);
    }
  }
#pragma unroll 1
  for (int ch = 1; ch < 32; ++ch) {
    float4 pj = pts[ch * 64 + lane];  // conflict-free b128
#pragma unroll
    for (int rr = 0; rr < 8; ++rr) {
      float key =
          2.f * (pi[rr].x * pj.x + pi[rr].y * pj.y + pi[rr].z * pj.z) - pj.w;
      unsigned long long x = pack_key(key, ch * 64 + lane);
      unsigned long long tau = rl64(t[rr], 0);
      unsigned long long mask = __ballot(x > tau);
      topk_drain(t[rr], x, mask);
    }
  }
  if (lane < K_) {
#pragma unroll
    for (int rr = 0; rr < 8; ++rr)
      idx[((size_t)b * P_ + row0 + rr) * K_ + lane] = (int)(~(unsigned)t[rr]);
  }
}

// ---------------- Kernel 2: bv1[i][c] = pos_i @ W1[3:6] ----------------
__global__ __launch_bounds__(256) void bv1_kernel(
    const float* __restrict__ pos, const float* __restrict__ W1,
    float* __restrict__ bv) {
  int t = blockIdx.x * 256 + threadIdx.x;  // over B*P*64
  int c = t & 63, i = t >> 6;
  const float* p = pos + (size_t)i * 3;
  bv[t] = p[0] * W1[3 * 64 + c] + p[1] * W1[4 * 64 + c] + p[2] * W1[5 * 64 + c];
}

// ---------------- Kernel 3: layer-1 edge MLP + max over K -> x1, d2 -----
__global__ __launch_bounds__(256) void layer1_kernel(
    const float* __restrict__ pos, const float* __restrict__ W1,
    const float* __restrict__ b1, const float* __restrict__ g1,
    const float* __restrict__ bt1, const float* __restrict__ W2,
    const float* __restrict__ b2, const int* __restrict__ idx,
    const float* __restrict__ bv, float* __restrict__ x1,
    float* __restrict__ d2out) {
  __shared__ __align__(16) float W2t[64 * 68];  // W2t[n][c] = W2[c][n]
  __shared__ __align__(16) float T[4][K_ * 64];
  int b = blockIdx.y;
  int lane = threadIdx.x & 63;
  int w = threadIdx.x >> 6;
  for (int t = threadIdx.x; t < 64 * 64; t += 256) {
    int c = t >> 6, n = t & 63;
    W2t[n * 68 + c] = W2[c * 64 + n];
  }
  int i = blockIdx.x * 4 + w;
  size_t ip = (size_t)b * P_ + i;
  const float* posi = pos + ip * 3;
  float px = posi[0], py = posi[1], pz = posi[2];
  int c = lane;
  float cv = px * (W1[0 * 64 + c] - W1[3 * 64 + c]) +
             py * (W1[1 * 64 + c] - W1[4 * 64 + c]) +
             pz * (W1[2 * 64 + c] - W1[5 * 64 + c]) + b1[c];
  float g = g1[c], bt = bt1[c];
  const int* ji = idx + ip * K_;
  const float* bvb = bv + (size_t)b * P_ * 64;
  for (int k = 0; k < K_; ++k) {
    int j = ji[k];
    float t = cv + bvb[(size_t)j * 64 + c];
    t = fmaxf(t * g + bt, 0.f);
    T[w][k * 64 + c] = t;
  }
  __syncthreads();
  float acc[K_];
#pragma unroll
  for (int k = 0; k < K_; ++k) acc[k] = 0.f;
  const float4* Trow = (const float4*)&T[w][0];
#pragma unroll
  for (int c4 = 0; c4 < 16; ++c4) {
    float4 wv = *(const float4*)&W2t[lane * 68 + c4 * 4];
#pragma unroll
    for (int k = 0; k < K_; ++k) {
      float4 tvv = Trow[k * 16 + c4];  // broadcast
      acc[k] += tvv.x * wv.x + tvv.y * wv.y + tvv.z * wv.z + tvv.w * wv.w;
    }
  }
  float m = -INFINITY;
#pragma unroll
  for (int k = 0; k < K_; ++k) m = fmaxf(m, acc[k]);
  m += b2[lane];
  x1[ip * 64 + lane] = m;
  float s = m * m;
#pragma unroll
  for (int off = 32; off; off >>= 1) s += __shfl_xor(s, off, 64);
  if (lane == 0) d2out[ip] = s;
}

// ---------------- Kernel 4a: Gram scores -> packed u32 keys (global) ----
// grid (32 row-panels, 2 col-halves, chunkB), block 256.
__global__ __launch_bounds__(256) void gemm_scores_kernel(
    const float* __restrict__ x1, const float* __restrict__ d2g,
    unsigned* __restrict__ scores, int chunkBase) {
  __shared__ __align__(16) float As[64 * 68];    // 17,408 B
  __shared__ __align__(16) float Bs[128 * 68];   // 34,816 B
  __shared__ float d2s[128];
  int bz = blockIdx.z;
  int b = chunkBase + bz;
  int r0 = blockIdx.x * 64;
  int c0 = blockIdx.y * 1024;
  const float* xb = x1 + (size_t)b * P_ * 64;
  unsigned* sb = scores + ((size_t)bz * P_ + r0) * P_;
  int tid = threadIdx.x;
  int tr = tid >> 4;  // 0..15 -> rows tr*4+a
  int tc = tid & 15;  // cols tc+16*c

  for (int g = tid; g < 64 * 16; g += 256) {
    int r = g >> 4, c4 = g & 15;
    *(float4*)&As[r * 68 + c4 * 4] =
        *(const float4*)(xb + (size_t)(r0 + r) * 64 + c4 * 4);
  }

#pragma unroll 1
  for (int tile = 0; tile < 8; ++tile) {
    int j0 = c0 + tile * 128;
    __syncthreads();  // previous tile's Bs reads done
    for (int g = tid; g < 128 * 16; g += 256) {
      int r = g >> 4, c4 = g & 15;
      *(float4*)&Bs[r * 68 + c4 * 4] =
          *(const float4*)(xb + (size_t)(j0 + r) * 64 + c4 * 4);
    }
    if (tid < 128) d2s[tid] = d2g[(size_t)b * P_ + j0 + tid];
    __syncthreads();

    float acc[4][8];
#pragma unroll
    for (int a = 0; a < 4; ++a)
#pragma unroll
      for (int c = 0; c < 8; ++c) acc[a][c] = 0.f;
#pragma unroll
    for (int c4 = 0; c4 < 16; ++c4) {
      float4 af[4], bf[8];
#pragma unroll
      for (int a = 0; a < 4; ++a)
        af[a] = *(const float4*)(&As[(tr * 4 + a) * 68 + c4 * 4]);
#pragma unroll
      for (int c = 0; c < 8; ++c)
        bf[c] = *(const float4*)(&Bs[(tc + 16 * c) * 68 + c4 * 4]);
#pragma unroll
      for (int a = 0; a < 4; ++a)
#pragma unroll
        for (int c = 0; c < 8; ++c) {
          float s = acc[a][c];
          s = fmaf(af[a].x, bf[c].x, s);
          s = fmaf(af[a].y, bf[c].y, s);
          s = fmaf(af[a].z, bf[c].z, s);
          s = fmaf(af[a].w, bf[c].w, s);
          acc[a][c] = s;
        }
    }
#pragma unroll
    for (int a = 0; a < 4; ++a)
#pragma unroll
      for (int c = 0; c < 8; ++c) {
        int col = tc + 16 * c;
        sb[(size_t)(tr * 4 + a) * P_ + j0 + col] =
            monok(2.f * acc[a][c] - d2s[col]);
      }
  }
}

// ---------------- Kernel 4b: select top-20 per row from key buffer ------
// grid (P/4, chunkB), block 256: one wave per row, no LDS.
__global__ __launch_bounds__(256) void knn_select_kernel(
    const unsigned* __restrict__ scores, int* __restrict__ idx,
    int chunkBase) {
  int bb = blockIdx.y;
  int b = chunkBase + bb;
  int row = blockIdx.x * 4 + (threadIdx.x >> 6);
  int lane = threadIdx.x & 63;
  const unsigned* sp = scores + ((size_t)bb * P_ + row) * P_;
  unsigned long long t;
  // it = 0: seed from first 64 keys (q==0), drain q=1..3
  {
    uint4 kv = *(const uint4*)(sp + lane * 4);
    int cb = lane * 4;
    t = topk_seed(((unsigned long long)kv.x << 32) | (unsigned)(~cb), lane);
#pragma unroll
    for (int q = 1; q < 4; ++q) {
      unsigned key = q == 1 ? kv.y : q == 2 ? kv.z : kv.w;
      unsigned long long x =
          ((unsigned long long)key << 32) | (unsigned)(~(cb + q));
      unsigned long long tau = rl64(t, 0);
      unsigned long long mask = __ballot(x > tau);
      topk_drain(t, x, mask);
    }
  }
#pragma unroll 1
  for (int it = 1; it < P_ / 256; ++it) {
    uint4 kv = *(const uint4*)(sp + it * 256 + lane * 4);
    int cb = it * 256 + lane * 4;
#pragma unroll
    for (int q = 0; q < 4; ++q) {
      unsigned key = q == 0 ? kv.x : q == 1 ? kv.y : q == 2 ? kv.z : kv.w;
      unsigned long long x =
          ((unsigned long long)key << 32) | (unsigned)(~(cb + q));
      unsigned long long tau = rl64(t, 0);
      unsigned long long mask = __ballot(x > tau);
      topk_drain(t, x, mask);
    }
  }
  if (lane < K_)
    idx[((size_t)b * P_ + row) * K_ + lane] = (int)(~(unsigned)t);
}

// ---------------- Kernel 5: e2 = x1@(W3a-W3b)+b3, bb2 = x1@W3b ----------
__global__ __launch_bounds__(256) void ebb_kernel(
    const float* __restrict__ x1, const float* __restrict__ W3,
    const float* __restrict__ b3, float* __restrict__ e2,
    float* __restrict__ bb2) {
  __shared__ float xs[16 * 64];
  size_t p0 = (size_t)blockIdx.x * 16;
  for (int v = threadIdx.x; v < 16 * 64; v += 256) xs[v] = x1[p0 * 64 + v];
  __syncthreads();
  int n = threadIdx.x & 127;
  int which = threadIdx.x >> 7;  // wave-uniform
  float acc[16];
#pragma unroll
  for (int p = 0; p < 16; ++p) acc[p] = 0.f;
  for (int c = 0; c < 64; ++c) {
    float wa = W3[c * 128 + n];
    float wb = W3[(64 + c) * 128 + n];
    float wv = which ? wb : (wa - wb);
#pragma unroll
    for (int p = 0; p < 16; ++p) acc[p] += xs[p * 64 + c] * wv;
  }
  float bias = which ? 0.f : b3[n];
  float* dst = which ? bb2 : e2;
#pragma unroll
  for (int p = 0; p < 16; ++p) dst[(p0 + p) * 128 + n] = acc[p] + bias;
}

// ---------------- Kernel 6: x2 gather-max + hp@Wl + per-tile max --------
__global__ __launch_bounds__(256) void final_kernel(
    const float* __restrict__ x1, const float* __restrict__ e2,
    const float* __restrict__ bb2, const int* __restrict__ idx,
    const float* __restrict__ Wl, const float* __restrict__ bl,
    float* __restrict__ partial) {
  __shared__ float hp[32][192];
  __shared__ float smax[2][128];
  int b = blockIdx.y;
  int i0 = blockIdx.x * 32;
  size_t gp0 = (size_t)b * P_ + i0;
  for (int v = threadIdx.x; v < 32 * 64; v += 256) {
    int p = v >> 6, c = v & 63;
    hp[p][c] = x1[(gp0 + p) * 64 + c];
  }
  for (int v = threadIdx.x; v < 32 * 128; v += 256) {
    int p = v >> 7, n = v & 127;
    size_t gp = gp0 + p;
    const int* ji = idx + gp * K_;
    float m = -INFINITY;
    for (int k = 0; k < K_; ++k) {
      int j = ji[k];
      m = fmaxf(m, bb2[((size_t)b * P_ + j) * 128 + n]);
    }
    hp[p][64 + n] = e2[gp * 128 + n] + m;
  }
  __syncthreads();
  int n = threadIdx.x & 127;
  int pg = threadIdx.x >> 7;
  float acc[16];
#pragma unroll
  for (int p = 0; p < 16; ++p) acc[p] = 0.f;
  for (int c = 0; c < 192; ++c) {
    float wv = Wl[c * 128 + n];
#pragma unroll
    for (int p = 0; p < 16; ++p) acc[p] += hp[pg * 16 + p][c] * wv;
  }
  float m = -INFINITY;
#pragma unroll
  for (int p = 0; p < 16; ++p) m = fmaxf(m, acc[p]);
  smax[pg][n] = m;
  __syncthreads();
  if (threadIdx.x < 128) {
    float v = fmaxf(smax[0][n], smax[1][n]) + bl[n];
    partial[((size_t)b * 64 + blockIdx.x) * 128 + n] = v;
  }
}

// ---------------- Kernel 7: reduce partial maxes -> out (B,128) ---------
__global__ __launch_bounds__(256) void reduce_kernel(
    const float* __restrict__ partial, float* __restrict__ out) {
  int t = blockIdx.x * 256 + threadIdx.x;  // 4096
  int b = t >> 7, n = t & 127;
  float m = -INFINITY;
  for (int tb = 0; tb < 64; ++tb)
    m = fmaxf(m, partial[((size_t)b * 64 + tb) * 128 + n]);
  out[t] = m;
}

extern "C" void kernel_launch(void* const* d_in, const int* in_sizes, int n_in,
                              void* d_out, int out_size, void* d_ws,
                              size_t ws_size, hipStream_t stream) {
  (void)in_sizes; (void)n_in; (void)out_size;
  const float* pos = (const float*)d_in[0];
  const float* W1  = (const float*)d_in[1];
  const float* b1  = (const float*)d_in[2];
  const float* g1  = (const float*)d_in[3];
  const float* bt1 = (const float*)d_in[4];
  const float* W2  = (const float*)d_in[5];
  const float* b2  = (const float*)d_in[6];
  const float* W3  = (const float*)d_in[7];
  const float* b3  = (const float*)d_in[8];
  const float* Wl  = (const float*)d_in[9];
  const float* bl  = (const float*)d_in[10];
  float* out = (float*)d_out;

  // Workspace layout (bytes), peak 90,439,680:
  //   [0, 5242880)          idx (idx1 then idx2)
  //   [5242880, 22020096)   x1
  //   [22020096, 22282240)  d2
  //   [22282240, 23330816)  partial
  //   [23330816, 90439680)  region (67,108,864): bv1 -> scores -> e2|bb2
  char* w = (char*)d_ws;
  int*      idxp  = (int*)(w + 0);
  float*    x1p   = (float*)(w + 5242880);
  float*    d2p   = (float*)(w + 22020096);
  float*    partp = (float*)(w + 22282240);
  float*    bv1p  = (float*)(w + 23330816);     // dead after layer1
  unsigned* scp   = (unsigned*)(w + 23330816);  // live only during kNN-2
  float*    e2p   = (float*)(w + 23330816);     // live after kNN-2
  float*    bb2p  = (float*)(w + 23330816 + 33554432);

  // Adaptive score-chunk: per batch 2048*2048*4 = 16,777,216 B.
  size_t avail = ws_size > 23330816 ? ws_size - 23330816 : 0;
  int chunkB = 4;  // guaranteed: region holds 4 x 16 MB
  if (avail >= (size_t)16 * 16777216) chunkB = 16;
  else if (avail >= (size_t)8 * 16777216) chunkB = 8;

  knn3_kernel<<<dim3(P_ / 32, B_), 256, 0, stream>>>(pos, idxp);
  bv1_kernel<<<dim3(B_ * P_ * 64 / 256), 256, 0, stream>>>(pos, W1, bv1p);
  layer1_kernel<<<dim3(P_ / 4, B_), 256, 0, stream>>>(
      pos, W1, b1, g1, bt1, W2, b2, idxp, bv1p, x1p, d2p);
  for (int cb = 0; cb < B_; cb += chunkB) {
    gemm_scores_kernel<<<dim3(32, 2, chunkB), 256, 0, stream>>>(
        x1p, d2p, scp, cb);
    knn_select_kernel<<<dim3(P_ / 4, chunkB), 256, 0, stream>>>(
        scp, idxp, cb);
  }
  ebb_kernel<<<dim3(B_ * P_ / 16), 256, 0, stream>>>(x1p, W3, b3, e2p, bb2p);
  final_kernel<<<dim3(P_ / 32, B_), 256, 0, stream>>>(
      x1p, e2p, bb2p, idxp, Wl, bl, partp);
  reduce_kernel<<<dim3(16), 256, 0, stream>>>(partp, out);
}

// Round 8
// 1042.773 us; speedup vs baseline: 2.7823x; 1.0541x over previous
//
#include <hip/hip_runtime.h>

#define B_ 32
#define P_ 2048
#define K_ 20

// ---- order-preserving (key, idx) packing -------------------------------
// larger key wins; ties -> smaller idx wins (matches jax.lax.top_k).
__device__ inline unsigned monok(float key) {
  unsigned u = __float_as_uint(key);
  return u ^ (((unsigned)((int)u >> 31)) | 0x80000000u);  // monotone f32->u32
}
__device__ inline float unmonok(unsigned u) {
  return __uint_as_float((u & 0x80000000u) ? (u ^ 0x80000000u) : ~u);
}
__device__ inline unsigned long long pack_key(float key, int j) {
  return ((unsigned long long)monok(key) << 32) | (unsigned)(~j);
}

// Full ascending bitonic sort of 64 u64 across the wave's lanes.
__device__ inline unsigned long long sort64(unsigned long long v, int lane) {
#pragma unroll
  for (int k = 2; k <= 64; k <<= 1) {
#pragma unroll
    for (int j = k >> 1; j > 0; j >>= 1) {
      unsigned long long o = __shfl_xor(v, j, 64);
      bool keepMin = ((lane & j) == 0) == ((lane & k) == 0);
      unsigned long long mn = v < o ? v : o;
      unsigned long long mx = v < o ? o : v;
      v = keepMin ? mn : mx;
    }
  }
  return v;
}

// Seed the wave-distributed top-20 list from 64 candidates (1/lane):
// sort ascending, move top-20 (lanes 44..63) to lanes 0..19, sentinel rest.
__device__ inline unsigned long long topk_seed(unsigned long long x, int lane) {
  unsigned long long s = sort64(x, lane);
  unsigned long long v = __shfl(s, lane + 44, 64);
  return (lane < K_) ? v : ~0ULL;
}

// ---- slim wave-distributed top-K drains --------------------------------
// List across lanes: lane k = k-th smallest kept (lane 0 = tau = 20th
// best), lanes >= K_ = ~0 sentinel. Ballot on raw key vs scalar tau
// (>= so key-ties fall through to the exact u64 compare); candidate u64
// built only on the insert path from one readlane + index recomputed
// from the ballot bit position (j = jbase + src*STRIDE).
template <int STRIDE>
__device__ inline void drain_f(unsigned long long& t, float keyf, int jbase,
                               unsigned& tauU, float& tauf) {
  unsigned long long mask = __ballot(keyf >= tauf);
  while (mask) {
    int src = (int)__builtin_ctzll(mask);
    mask &= mask - 1;
    unsigned kb = (unsigned)__builtin_amdgcn_readlane(__float_as_int(keyf), src);
    unsigned kU = kb ^ (((unsigned)((int)kb >> 31)) | 0x80000000u);
    if (kU < tauU) continue;  // stale (scalar cmp+branch)
    unsigned long long xi =
        ((unsigned long long)kU << 32) | (unsigned)(~(jbase + src * STRIDE));
    unsigned long long up = __shfl_down(t, 1, 64);
    bool c1 = t < xi;
    bool c2 = up < xi;
    unsigned long long v = c1 ? xi : t;
    t = c2 ? up : v;
    tauU = (unsigned)__builtin_amdgcn_readlane((int)(unsigned)(t >> 32), 0);
    tauf = unmonok(tauU);
  }
}
template <int STRIDE>
__device__ inline void drain_u(unsigned long long& t, unsigned keyU, int jbase,
                               unsigned& tauU) {
  unsigned long long mask = __ballot(keyU >= tauU);
  while (mask) {
    int src = (int)__builtin_ctzll(mask);
    mask &= mask - 1;
    unsigned kU = (unsigned)__builtin_amdgcn_readlane((int)keyU, src);
    if (kU < tauU) continue;
    unsigned long long xi =
        ((unsigned long long)kU << 32) | (unsigned)(~(jbase + src * STRIDE));
    unsigned long long up = __shfl_down(t, 1, 64);
    bool c1 = t < xi;
    bool c2 = up < xi;
    unsigned long long v = c1 ? xi : t;
    t = c2 ? up : v;
    tauU = (unsigned)__builtin_amdgcn_readlane((int)(unsigned)(t >> 32), 0);
  }
}

// ---------------- Kernel 1: kNN on 3-D positions -> idx1 ----------------
// grid (P/32, B), block 256 (4 waves). Wave w owns rows w*8..w*8+7.
__global__ __launch_bounds__(256) void knn3_kernel(
    const float* __restrict__ pos, int* __restrict__ idx) {
  __shared__ float4 pts[P_];  // 32 KB: x,y,z,d2
  int b = blockIdx.y;
  const float* bp = pos + (size_t)b * P_ * 3;
  for (int j = threadIdx.x; j < P_; j += 256) {
    float x = bp[j * 3 + 0], y = bp[j * 3 + 1], z = bp[j * 3 + 2];
    pts[j] = make_float4(x, y, z, x * x + y * y + z * z);
  }
  __syncthreads();
  int wv = threadIdx.x >> 6;
  int lane = threadIdx.x & 63;
  int row0 = blockIdx.x * 32 + wv * 8;
  float4 pi[8];
#pragma unroll
  for (int rr = 0; rr < 8; ++rr) {
    float4 p = pts[row0 + rr];  // uniform reads
    pi[rr] = make_float4(2.f * p.x, 2.f * p.y, 2.f * p.z, p.w);
  }
  unsigned long long t[8];
  unsigned tauU[8];
  float tauf[8];
  // chunk 0: bitonic sort-seed (replaces 64 serial drains per row)
  {
    float4 pj = pts[lane];
#pragma unroll
    for (int rr = 0; rr < 8; ++rr) {
      float key = fmaf(pi[rr].x, pj.x,
                  fmaf(pi[rr].y, pj.y, fmaf(pi[rr].z, pj.z, -pj.w)));
      t[rr] = topk_seed(pack_key(key, lane), lane);
      tauU[rr] = (unsigned)__builtin_amdgcn_readlane(
          (int)(unsigned)(t[rr] >> 32), 0);
      tauf[rr] = unmonok(tauU[rr]);
    }
  }
#pragma unroll 1
  for (int ch = 1; ch < 32; ++ch) {
    float4 pj = pts[ch * 64 + lane];  // conflict-free b128
#pragma unroll
    for (int rr = 0; rr < 8; ++rr) {
      float key = fmaf(pi[rr].x, pj.x,
                  fmaf(pi[rr].y, pj.y, fmaf(pi[rr].z, pj.z, -pj.w)));
      drain_f<1>(t[rr], key, ch * 64, tauU[rr], tauf[rr]);
    }
  }
  if (lane < K_) {
#pragma unroll
    for (int rr = 0; rr < 8; ++rr)
      idx[((size_t)b * P_ + row0 + rr) * K_ + lane] = (int)(~(unsigned)t[rr]);
  }
}

// ---------------- Kernel 2: bv1[i][c] = pos_i @ W1[3:6] ----------------
__global__ __launch_bounds__(256) void bv1_kernel(
    const float* __restrict__ pos, const float* __restrict__ W1,
    float* __restrict__ bv) {
  int t = blockIdx.x * 256 + threadIdx.x;  // over B*P*64
  int c = t & 63, i = t >> 6;
  const float* p = pos + (size_t)i * 3;
  bv[t] = p[0] * W1[3 * 64 + c] + p[1] * W1[4 * 64 + c] + p[2] * W1[5 * 64 + c];
}

// ---------------- Kernel 3: layer-1 edge MLP + max over K -> x1, d2 -----
__global__ __launch_bounds__(256) void layer1_kernel(
    const float* __restrict__ pos, const float* __restrict__ W1,
    const float* __restrict__ b1, const float* __restrict__ g1,
    const float* __restrict__ bt1, const float* __restrict__ W2,
    const float* __restrict__ b2, const int* __restrict__ idx,
    const float* __restrict__ bv, float* __restrict__ x1,
    float* __restrict__ d2out) {
  __shared__ __align__(16) float W2t[64 * 68];  // W2t[n][c] = W2[c][n]
  __shared__ __align__(16) float T[4][K_ * 64];
  int b = blockIdx.y;
  int lane = threadIdx.x & 63;
  int w = threadIdx.x >> 6;
  for (int t = threadIdx.x; t < 64 * 64; t += 256) {
    int c = t >> 6, n = t & 63;
    W2t[n * 68 + c] = W2[c * 64 + n];
  }
  int i = blockIdx.x * 4 + w;
  size_t ip = (size_t)b * P_ + i;
  const float* posi = pos + ip * 3;
  float px = posi[0], py = posi[1], pz = posi[2];
  int c = lane;
  float cv = px * (W1[0 * 64 + c] - W1[3 * 64 + c]) +
             py * (W1[1 * 64 + c] - W1[4 * 64 + c]) +
             pz * (W1[2 * 64 + c] - W1[5 * 64 + c]) + b1[c];
  float g = g1[c], bt = bt1[c];
  const int* ji = idx + ip * K_;
  const float* bvb = bv + (size_t)b * P_ * 64;
  for (int k = 0; k < K_; ++k) {
    int j = ji[k];
    float t = cv + bvb[(size_t)j * 64 + c];
    t = fmaxf(t * g + bt, 0.f);
    T[w][k * 64 + c] = t;
  }
  __syncthreads();
  float acc[K_];
#pragma unroll
  for (int k = 0; k < K_; ++k) acc[k] = 0.f;
  const float4* Trow = (const float4*)&T[w][0];
#pragma unroll
  for (int c4 = 0; c4 < 16; ++c4) {
    float4 wv = *(const float4*)&W2t[lane * 68 + c4 * 4];
#pragma unroll
    for (int k = 0; k < K_; ++k) {
      float4 tvv = Trow[k * 16 + c4];  // broadcast
      acc[k] += tvv.x * wv.x + tvv.y * wv.y + tvv.z * wv.z + tvv.w * wv.w;
    }
  }
  float m = -INFINITY;
#pragma unroll
  for (int k = 0; k < K_; ++k) m = fmaxf(m, acc[k]);
  m += b2[lane];
  x1[ip * 64 + lane] = m;
  float s = m * m;
#pragma unroll
  for (int off = 32; off; off >>= 1) s += __shfl_xor(s, off, 64);
  if (lane == 0) d2out[ip] = s;
}

// ---------------- Kernel 4a: Gram scores -> packed u32 keys (global) ----
// grid (32 row-panels, 4 col-quarters, chunkB), block 256.
__global__ __launch_bounds__(256) void gemm_scores_kernel(
    const float* __restrict__ x1, const float* __restrict__ d2g,
    unsigned* __restrict__ scores, int chunkBase) {
  __shared__ __align__(16) float As[64 * 68];    // 17,408 B
  __shared__ __align__(16) float Bs[128 * 68];   // 34,816 B
  __shared__ float d2s[128];
  int bz = blockIdx.z;
  int b = chunkBase + bz;
  int r0 = blockIdx.x * 64;
  int c0 = blockIdx.y * 512;
  const float* xb = x1 + (size_t)b * P_ * 64;
  unsigned* sb = scores + ((size_t)bz * P_ + r0) * P_;
  int tid = threadIdx.x;
  int tr = tid >> 4;  // 0..15 -> rows tr*4+a
  int tc = tid & 15;  // cols tc+16*c

  for (int g = tid; g < 64 * 16; g += 256) {
    int r = g >> 4, c4 = g & 15;
    *(float4*)&As[r * 68 + c4 * 4] =
        *(const float4*)(xb + (size_t)(r0 + r) * 64 + c4 * 4);
  }

#pragma unroll 1
  for (int tile = 0; tile < 4; ++tile) {
    int j0 = c0 + tile * 128;
    __syncthreads();  // previous tile's Bs reads done
    for (int g = tid; g < 128 * 16; g += 256) {
      int r = g >> 4, c4 = g & 15;
      *(float4*)&Bs[r * 68 + c4 * 4] =
          *(const float4*)(xb + (size_t)(j0 + r) * 64 + c4 * 4);
    }
    if (tid < 128) d2s[tid] = d2g[(size_t)b * P_ + j0 + tid];
    __syncthreads();

    float acc[4][8];
#pragma unroll
    for (int a = 0; a < 4; ++a)
#pragma unroll
      for (int c = 0; c < 8; ++c) acc[a][c] = 0.f;
#pragma unroll
    for (int c4 = 0; c4 < 16; ++c4) {
      float4 af[4], bf[8];
#pragma unroll
      for (int a = 0; a < 4; ++a)
        af[a] = *(const float4*)(&As[(tr * 4 + a) * 68 + c4 * 4]);
#pragma unroll
      for (int c = 0; c < 8; ++c)
        bf[c] = *(const float4*)(&Bs[(tc + 16 * c) * 68 + c4 * 4]);
#pragma unroll
      for (int a = 0; a < 4; ++a)
#pragma unroll
        for (int c = 0; c < 8; ++c) {
          float s = acc[a][c];
          s = fmaf(af[a].x, bf[c].x, s);
          s = fmaf(af[a].y, bf[c].y, s);
          s = fmaf(af[a].z, bf[c].z, s);
          s = fmaf(af[a].w, bf[c].w, s);
          acc[a][c] = s;
        }
    }
#pragma unroll
    for (int a = 0; a < 4; ++a)
#pragma unroll
      for (int c = 0; c < 8; ++c) {
        int col = tc + 16 * c;
        sb[(size_t)(tr * 4 + a) * P_ + j0 + col] =
            monok(2.f * acc[a][c] - d2s[col]);
      }
  }
}

// ---------------- Kernel 4b: select top-20 per row from key buffer ------
// grid (P/4, chunkB), block 256: one wave per row, no LDS.
__global__ __launch_bounds__(256) void knn_select_kernel(
    const unsigned* __restrict__ scores, int* __restrict__ idx,
    int chunkBase) {
  int bb = blockIdx.y;
  int b = chunkBase + bb;
  int row = blockIdx.x * 4 + (threadIdx.x >> 6);
  int lane = threadIdx.x & 63;
  const unsigned* sp = scores + ((size_t)bb * P_ + row) * P_;
  unsigned long long t;
  unsigned tauU;
  // it = 0: seed from first stripe (q==0), drain q=1..3
  {
    uint4 kv = *(const uint4*)(sp + lane * 4);
    t = topk_seed(((unsigned long long)kv.x << 32) | (unsigned)(~(lane * 4)),
                  lane);
    tauU = (unsigned)__builtin_amdgcn_readlane((int)(unsigned)(t >> 32), 0);
    drain_u<4>(t, kv.y, 1, tauU);
    drain_u<4>(t, kv.z, 2, tauU);
    drain_u<4>(t, kv.w, 3, tauU);
  }
#pragma unroll 1
  for (int it = 1; it < P_ / 256; ++it) {
    uint4 kv = *(const uint4*)(sp + it * 256 + lane * 4);
    int cb = it * 256;
    drain_u<4>(t, kv.x, cb + 0, tauU);
    drain_u<4>(t, kv.y, cb + 1, tauU);
    drain_u<4>(t, kv.z, cb + 2, tauU);
    drain_u<4>(t, kv.w, cb + 3, tauU);
  }
  if (lane < K_)
    idx[((size_t)b * P_ + row) * K_ + lane] = (int)(~(unsigned)t);
}

// ---------------- Kernel 5: e2 = x1@(W3a-W3b)+b3, bb2 = x1@W3b ----------
__global__ __launch_bounds__(256) void ebb_kernel(
    const float* __restrict__ x1, const float* __restrict__ W3,
    const float* __restrict__ b3, float* __restrict__ e2,
    float* __restrict__ bb2) {
  __shared__ float xs[16 * 64];
  size_t p0 = (size_t)blockIdx.x * 16;
  for (int v = threadIdx.x; v < 16 * 64; v += 256) xs[v] = x1[p0 * 64 + v];
  __syncthreads();
  int n = threadIdx.x & 127;
  int which = threadIdx.x >> 7;  // wave-uniform
  float acc[16];
#pragma unroll
  for (int p = 0; p < 16; ++p) acc[p] = 0.f;
  for (int c = 0; c < 64; ++c) {
    float wa = W3[c * 128 + n];
    float wb = W3[(64 + c) * 128 + n];
    float wv = which ? wb : (wa - wb);
#pragma unroll
    for (int p = 0; p < 16; ++p) acc[p] += xs[p * 64 + c] * wv;
  }
  float bias = which ? 0.f : b3[n];
  float* dst = which ? bb2 : e2;
#pragma unroll
  for (int p = 0; p < 16; ++p) dst[(p0 + p) * 128 + n] = acc[p] + bias;
}

// ---------------- Kernel 6: x2 gather-max + hp@Wl + per-tile max --------
__global__ __launch_bounds__(256) void final_kernel(
    const float* __restrict__ x1, const float* __restrict__ e2,
    const float* __restrict__ bb2, const int* __restrict__ idx,
    const float* __restrict__ Wl, const float* __restrict__ bl,
    float* __restrict__ partial) {
  __shared__ float hp[32][192];
  __shared__ float smax[2][128];
  int b = blockIdx.y;
  int i0 = blockIdx.x * 32;
  size_t gp0 = (size_t)b * P_ + i0;
  for (int v = threadIdx.x; v < 32 * 64; v += 256) {
    int p = v >> 6, c = v & 63;
    hp[p][c] = x1[(gp0 + p) * 64 + c];
  }
  for (int v = threadIdx.x; v < 32 * 128; v += 256) {
    int p = v >> 7, n = v & 127;
    size_t gp = gp0 + p;
    const int* ji = idx + gp * K_;
    float m = -INFINITY;
    for (int k = 0; k < K_; ++k) {
      int j = ji[k];
      m = fmaxf(m, bb2[((size_t)b * P_ + j) * 128 + n]);
    }
    hp[p][64 + n] = e2[gp * 128 + n] + m;
  }
  __syncthreads();
  int n = threadIdx.x & 127;
  int pg = threadIdx.x >> 7;
  float acc[16];
#pragma unroll
  for (int p = 0; p < 16; ++p) acc[p] = 0.f;
  for (int c = 0; c < 192; ++c) {
    float wv = Wl[c * 128 + n];
#pragma unroll
    for (int p = 0; p < 16; ++p) acc[p] += hp[pg * 16 + p][c] * wv;
  }
  float m = -INFINITY;
#pragma unroll
  for (int p = 0; p < 16; ++p) m = fmaxf(m, acc[p]);
  smax[pg][n] = m;
  __syncthreads();
  if (threadIdx.x < 128) {
    float v = fmaxf(smax[0][n], smax[1][n]) + bl[n];
    partial[((size_t)b * 64 + blockIdx.x) * 128 + n] = v;
  }
}

// ---------------- Kernel 7: reduce partial maxes -> out (B,128) ---------
__global__ __launch_bounds__(256) void reduce_kernel(
    const float* __restrict__ partial, float* __restrict__ out) {
  int t = blockIdx.x * 256 + threadIdx.x;  // 4096
  int b = t >> 7, n = t & 127;
  float m = -INFINITY;
  for (int tb = 0; tb < 64; ++tb)
    m = fmaxf(m, partial[((size_t)b * 64 + tb) * 128 + n]);
  out[t] = m;
}

extern "C" void kernel_launch(void* const* d_in, const int* in_sizes, int n_in,
                              void* d_out, int out_size, void* d_ws,
                              size_t ws_size, hipStream_t stream) {
  (void)in_sizes; (void)n_in; (void)out_size;
  const float* pos = (const float*)d_in[0];
  const float* W1  = (const float*)d_in[1];
  const float* b1  = (const float*)d_in[2];
  const float* g1  = (const float*)d_in[3];
  const float* bt1 = (const float*)d_in[4];
  const float* W2  = (const float*)d_in[5];
  const float* b2  = (const float*)d_in[6];
  const float* W3  = (const float*)d_in[7];
  const float* b3  = (const float*)d_in[8];
  const float* Wl  = (const float*)d_in[9];
  const float* bl  = (const float*)d_in[10];
  float* out = (float*)d_out;

  // Workspace layout (bytes), peak 90,439,680:
  //   [0, 5242880)          idx (idx1 then idx2)
  //   [5242880, 22020096)   x1
  //   [22020096, 22282240)  d2
  //   [22282240, 23330816)  partial
  //   [23330816, 90439680)  region (67,108,864): bv1 -> scores -> e2|bb2
  char* w = (char*)d_ws;
  int*      idxp  = (int*)(w + 0);
  float*    x1p   = (float*)(w + 5242880);
  float*    d2p   = (float*)(w + 22020096);
  float*    partp = (float*)(w + 22282240);
  float*    bv1p  = (float*)(w + 23330816);     // dead after layer1
  unsigned* scp   = (unsigned*)(w + 23330816);  // live only during kNN-2
  float*    e2p   = (float*)(w + 23330816);     // live after kNN-2
  float*    bb2p  = (float*)(w + 23330816 + 33554432);

  // Adaptive score-chunk: per batch 2048*2048*4 = 16,777,216 B.
  size_t avail = ws_size > 23330816 ? ws_size - 23330816 : 0;
  int chunkB = 4;  // guaranteed: region holds 4 x 16 MB
  if (avail >= (size_t)32 * 16777216) chunkB = 32;
  else if (avail >= (size_t)16 * 16777216) chunkB = 16;
  else if (avail >= (size_t)8 * 16777216) chunkB = 8;

  knn3_kernel<<<dim3(P_ / 32, B_), 256, 0, stream>>>(pos, idxp);
  bv1_kernel<<<dim3(B_ * P_ * 64 / 256), 256, 0, stream>>>(pos, W1, bv1p);
  layer1_kernel<<<dim3(P_ / 4, B_), 256, 0, stream>>>(
      pos, W1, b1, g1, bt1, W2, b2, idxp, bv1p, x1p, d2p);
  for (int cb = 0; cb < B_; cb += chunkB) {
    gemm_scores_kernel<<<dim3(32, 4, chunkB), 256, 0, stream>>>(
        x1p, d2p, scp, cb);
    knn_select_kernel<<<dim3(P_ / 4, chunkB), 256, 0, stream>>>(
        scp, idxp, cb);
  }
  ebb_kernel<<<dim3(B_ * P_ / 16), 256, 0, stream>>>(x1p, W3, b3, e2p, bb2p);
  final_kernel<<<dim3(P_ / 32, B_), 256, 0, stream>>>(
      x1p, e2p, bb2p, idxp, Wl, bl, partp);
  reduce_kernel<<<dim3(16), 256, 0, stream>>>(partp, out);
}

// Round 9
// 1019.258 us; speedup vs baseline: 2.8465x; 1.0231x over previous
//
#include <hip/hip_runtime.h>

#define B_ 32
#define P_ 2048
#define K_ 20

// ---- order-preserving (key, idx) packing -------------------------------
// larger key wins; ties -> smaller idx wins (matches jax.lax.top_k).
__device__ inline unsigned monok(float key) {
  unsigned u = __float_as_uint(key);
  return u ^ (((unsigned)((int)u >> 31)) | 0x80000000u);  // monotone f32->u32
}
__device__ inline float unmonok(unsigned u) {
  return __uint_as_float((u & 0x80000000u) ? (u ^ 0x80000000u) : ~u);
}
__device__ inline unsigned long long pack_key(float key, int j) {
  return ((unsigned long long)monok(key) << 32) | (unsigned)(~j);
}

// Full ascending bitonic sort of 64 u64 across the wave's lanes.
__device__ inline unsigned long long sort64(unsigned long long v, int lane) {
#pragma unroll
  for (int k = 2; k <= 64; k <<= 1) {
#pragma unroll
    for (int j = k >> 1; j > 0; j >>= 1) {
      unsigned long long o = __shfl_xor(v, j, 64);
      bool keepMin = ((lane & j) == 0) == ((lane & k) == 0);
      unsigned long long mn = v < o ? v : o;
      unsigned long long mx = v < o ? o : v;
      v = keepMin ? mn : mx;
    }
  }
  return v;
}

// Seed the wave-distributed top-20 list from 64 candidates (1/lane):
// sort ascending, move top-20 (lanes 44..63) to lanes 0..19, sentinel rest.
__device__ inline unsigned long long topk_seed(unsigned long long x, int lane) {
  unsigned long long s = sort64(x, lane);
  unsigned long long v = __shfl(s, lane + 44, 64);
  return (lane < K_) ? v : ~0ULL;
}

// ---- slim wave-distributed top-K drains --------------------------------
// List across lanes: lane k = k-th smallest kept (lane 0 = tau = 20th
// best), lanes >= K_ = ~0 sentinel. Ballot on raw key vs scalar tau
// (>= so key-ties fall through to the exact u64 compare); candidate u64
// built only on the insert path from one readlane + index recomputed
// from the ballot bit position (j = jbase + src*STRIDE).
template <int STRIDE>
__device__ inline void drain_f(unsigned long long& t, float keyf, int jbase,
                               unsigned& tauU, float& tauf) {
  unsigned long long mask = __ballot(keyf >= tauf);
  while (mask) {
    int src = (int)__builtin_ctzll(mask);
    mask &= mask - 1;
    unsigned kb = (unsigned)__builtin_amdgcn_readlane(__float_as_int(keyf), src);
    unsigned kU = kb ^ (((unsigned)((int)kb >> 31)) | 0x80000000u);
    if (kU < tauU) continue;  // stale (scalar cmp+branch)
    unsigned long long xi =
        ((unsigned long long)kU << 32) | (unsigned)(~(jbase + src * STRIDE));
    unsigned long long up = __shfl_down(t, 1, 64);
    bool c1 = t < xi;
    bool c2 = up < xi;
    unsigned long long v = c1 ? xi : t;
    t = c2 ? up : v;
    tauU = (unsigned)__builtin_amdgcn_readlane((int)(unsigned)(t >> 32), 0);
    tauf = unmonok(tauU);
  }
}
template <int STRIDE>
__device__ inline void drain_u(unsigned long long& t, unsigned keyU, int jbase,
                               unsigned& tauU) {
  unsigned long long mask = __ballot(keyU >= tauU);
  while (mask) {
    int src = (int)__builtin_ctzll(mask);
    mask &= mask - 1;
    unsigned kU = (unsigned)__builtin_amdgcn_readlane((int)keyU, src);
    if (kU < tauU) continue;
    unsigned long long xi =
        ((unsigned long long)kU << 32) | (unsigned)(~(jbase + src * STRIDE));
    unsigned long long up = __shfl_down(t, 1, 64);
    bool c1 = t < xi;
    bool c2 = up < xi;
    unsigned long long v = c1 ? xi : t;
    t = c2 ? up : v;
    tauU = (unsigned)__builtin_amdgcn_readlane((int)(unsigned)(t >> 32), 0);
  }
}

// ---------------- Kernel 1: kNN on 3-D positions -> idx1 ----------------
// grid (P/64, B) = 1024 blocks, block 512 (8 waves): exactly 4 blocks/CU
// (4 x 32KB LDS = 128KB), whole grid co-resident -> 32 waves/CU to hide
// the drain chain's shfl/branch latency. Wave w owns rows w*8..w*8+7.
__global__ __launch_bounds__(512) void knn3_kernel(
    const float* __restrict__ pos, int* __restrict__ idx) {
  __shared__ float4 pts[P_];  // 32 KB: x,y,z,d2
  int b = blockIdx.y;
  const float* bp = pos + (size_t)b * P_ * 3;
  for (int j = threadIdx.x; j < P_; j += 512) {
    float x = bp[j * 3 + 0], y = bp[j * 3 + 1], z = bp[j * 3 + 2];
    pts[j] = make_float4(x, y, z, x * x + y * y + z * z);
  }
  __syncthreads();
  int wv = threadIdx.x >> 6;
  int lane = threadIdx.x & 63;
  int row0 = blockIdx.x * 64 + wv * 8;
  float4 pi[8];
#pragma unroll
  for (int rr = 0; rr < 8; ++rr) {
    float4 p = pts[row0 + rr];  // uniform reads
    pi[rr] = make_float4(2.f * p.x, 2.f * p.y, 2.f * p.z, p.w);
  }
  unsigned long long t[8];
  unsigned tauU[8];
  float tauf[8];
  // chunk 0: bitonic sort-seed (replaces 64 serial drains per row)
  {
    float4 pj = pts[lane];
#pragma unroll
    for (int rr = 0; rr < 8; ++rr) {
      float key = fmaf(pi[rr].x, pj.x,
                  fmaf(pi[rr].y, pj.y, fmaf(pi[rr].z, pj.z, -pj.w)));
      t[rr] = topk_seed(pack_key(key, lane), lane);
      tauU[rr] = (unsigned)__builtin_amdgcn_readlane(
          (int)(unsigned)(t[rr] >> 32), 0);
      tauf[rr] = unmonok(tauU[rr]);
    }
  }
#pragma unroll 1
  for (int ch = 1; ch < 32; ++ch) {
    float4 pj = pts[ch * 64 + lane];  // conflict-free b128
#pragma unroll
    for (int rr = 0; rr < 8; ++rr) {
      float key = fmaf(pi[rr].x, pj.x,
                  fmaf(pi[rr].y, pj.y, fmaf(pi[rr].z, pj.z, -pj.w)));
      drain_f<1>(t[rr], key, ch * 64, tauU[rr], tauf[rr]);
    }
  }
  if (lane < K_) {
#pragma unroll
    for (int rr = 0; rr < 8; ++rr)
      idx[((size_t)b * P_ + row0 + rr) * K_ + lane] = (int)(~(unsigned)t[rr]);
  }
}

// ---------------- Kernel 2: bv1[i][c] = pos_i @ W1[3:6] ----------------
__global__ __launch_bounds__(256) void bv1_kernel(
    const float* __restrict__ pos, const float* __restrict__ W1,
    float* __restrict__ bv) {
  int t = blockIdx.x * 256 + threadIdx.x;  // over B*P*64
  int c = t & 63, i = t >> 6;
  const float* p = pos + (size_t)i * 3;
  bv[t] = p[0] * W1[3 * 64 + c] + p[1] * W1[4 * 64 + c] + p[2] * W1[5 * 64 + c];
}

// ---------------- Kernel 3: layer-1 edge MLP + max over K -> x1, d2 -----
__global__ __launch_bounds__(256) void layer1_kernel(
    const float* __restrict__ pos, const float* __restrict__ W1,
    const float* __restrict__ b1, const float* __restrict__ g1,
    const float* __restrict__ bt1, const float* __restrict__ W2,
    const float* __restrict__ b2, const int* __restrict__ idx,
    const float* __restrict__ bv, float* __restrict__ x1,
    float* __restrict__ d2out) {
  __shared__ __align__(16) float W2t[64 * 68];  // W2t[n][c] = W2[c][n]
  __shared__ __align__(16) float T[4][K_ * 64];
  int b = blockIdx.y;
  int lane = threadIdx.x & 63;
  int w = threadIdx.x >> 6;
  for (int t = threadIdx.x; t < 64 * 64; t += 256) {
    int c = t >> 6, n = t & 63;
    W2t[n * 68 + c] = W2[c * 64 + n];
  }
  int i = blockIdx.x * 4 + w;
  size_t ip = (size_t)b * P_ + i;
  const float* posi = pos + ip * 3;
  float px = posi[0], py = posi[1], pz = posi[2];
  int c = lane;
  float cv = px * (W1[0 * 64 + c] - W1[3 * 64 + c]) +
             py * (W1[1 * 64 + c] - W1[4 * 64 + c]) +
             pz * (W1[2 * 64 + c] - W1[5 * 64 + c]) + b1[c];
  float g = g1[c], bt = bt1[c];
  const int* ji = idx + ip * K_;
  const float* bvb = bv + (size_t)b * P_ * 64;
  for (int k = 0; k < K_; ++k) {
    int j = ji[k];
    float t = cv + bvb[(size_t)j * 64 + c];
    t = fmaxf(t * g + bt, 0.f);
    T[w][k * 64 + c] = t;
  }
  __syncthreads();
  float acc[K_];
#pragma unroll
  for (int k = 0; k < K_; ++k) acc[k] = 0.f;
  const float4* Trow = (const float4*)&T[w][0];
#pragma unroll
  for (int c4 = 0; c4 < 16; ++c4) {
    float4 wv = *(const float4*)&W2t[lane * 68 + c4 * 4];
#pragma unroll
    for (int k = 0; k < K_; ++k) {
      float4 tvv = Trow[k * 16 + c4];  // broadcast
      acc[k] += tvv.x * wv.x + tvv.y * wv.y + tvv.z * wv.z + tvv.w * wv.w;
    }
  }
  float m = -INFINITY;
#pragma unroll
  for (int k = 0; k < K_; ++k) m = fmaxf(m, acc[k]);
  m += b2[lane];
  x1[ip * 64 + lane] = m;
  float s = m * m;
#pragma unroll
  for (int off = 32; off; off >>= 1) s += __shfl_xor(s, off, 64);
  if (lane == 0) d2out[ip] = s;
}

// ---------------- Kernel 4a: Gram scores -> packed u32 keys (global) ----
// grid (32 row-panels, 4 col-quarters, chunkB), block 256.
__global__ __launch_bounds__(256) void gemm_scores_kernel(
    const float* __restrict__ x1, const float* __restrict__ d2g,
    unsigned* __restrict__ scores, int chunkBase) {
  __shared__ __align__(16) float As[64 * 68];    // 17,408 B
  __shared__ __align__(16) float Bs[128 * 68];   // 34,816 B
  __shared__ float d2s[128];
  int bz = blockIdx.z;
  int b = chunkBase + bz;
  int r0 = blockIdx.x * 64;
  int c0 = blockIdx.y * 512;
  const float* xb = x1 + (size_t)b * P_ * 64;
  unsigned* sb = scores + ((size_t)bz * P_ + r0) * P_;
  int tid = threadIdx.x;
  int tr = tid >> 4;  // 0..15 -> rows tr*4+a
  int tc = tid & 15;  // cols tc+16*c

  for (int g = tid; g < 64 * 16; g += 256) {
    int r = g >> 4, c4 = g & 15;
    *(float4*)&As[r * 68 + c4 * 4] =
        *(const float4*)(xb + (size_t)(r0 + r) * 64 + c4 * 4);
  }

#pragma unroll 1
  for (int tile = 0; tile < 4; ++tile) {
    int j0 = c0 + tile * 128;
    __syncthreads();  // previous tile's Bs reads done
    for (int g = tid; g < 128 * 16; g += 256) {
      int r = g >> 4, c4 = g & 15;
      *(float4*)&Bs[r * 68 + c4 * 4] =
          *(const float4*)(xb + (size_t)(j0 + r) * 64 + c4 * 4);
    }
    if (tid < 128) d2s[tid] = d2g[(size_t)b * P_ + j0 + tid];
    __syncthreads();

    float acc[4][8];
#pragma unroll
    for (int a = 0; a < 4; ++a)
#pragma unroll
      for (int c = 0; c < 8; ++c) acc[a][c] = 0.f;
#pragma unroll
    for (int c4 = 0; c4 < 16; ++c4) {
      float4 af[4], bf[8];
#pragma unroll
      for (int a = 0; a < 4; ++a)
        af[a] = *(const float4*)(&As[(tr * 4 + a) * 68 + c4 * 4]);
#pragma unroll
      for (int c = 0; c < 8; ++c)
        bf[c] = *(const float4*)(&Bs[(tc + 16 * c) * 68 + c4 * 4]);
#pragma unroll
      for (int a = 0; a < 4; ++a)
#pragma unroll
        for (int c = 0; c < 8; ++c) {
          float s = acc[a][c];
          s = fmaf(af[a].x, bf[c].x, s);
          s = fmaf(af[a].y, bf[c].y, s);
          s = fmaf(af[a].z, bf[c].z, s);
          s = fmaf(af[a].w, bf[c].w, s);
          acc[a][c] = s;
        }
    }
#pragma unroll
    for (int a = 0; a < 4; ++a)
#pragma unroll
      for (int c = 0; c < 8; ++c) {
        int col = tc + 16 * c;
        sb[(size_t)(tr * 4 + a) * P_ + j0 + col] =
            monok(2.f * acc[a][c] - d2s[col]);
      }
  }
}

// ---------------- Kernel 4b: select top-20 per row from key buffer ------
// grid (P/4, chunkB), block 256: one wave per row, no LDS.
__global__ __launch_bounds__(256) void knn_select_kernel(
    const unsigned* __restrict__ scores, int* __restrict__ idx,
    int chunkBase) {
  int bb = blockIdx.y;
  int b = chunkBase + bb;
  int row = blockIdx.x * 4 + (threadIdx.x >> 6);
  int lane = threadIdx.x & 63;
  const unsigned* sp = scores + ((size_t)bb * P_ + row) * P_;
  unsigned long long t;
  unsigned tauU;
  // it = 0: seed from first stripe (q==0), drain q=1..3
  {
    uint4 kv = *(const uint4*)(sp + lane * 4);
    t = topk_seed(((unsigned long long)kv.x << 32) | (unsigned)(~(lane * 4)),
                  lane);
    tauU = (unsigned)__builtin_amdgcn_readlane((int)(unsigned)(t >> 32), 0);
    drain_u<4>(t, kv.y, 1, tauU);
    drain_u<4>(t, kv.z, 2, tauU);
    drain_u<4>(t, kv.w, 3, tauU);
  }
#pragma unroll 1
  for (int it = 1; it < P_ / 256; ++it) {
    uint4 kv = *(const uint4*)(sp + it * 256 + lane * 4);
    int cb = it * 256;
    drain_u<4>(t, kv.x, cb + 0, tauU);
    drain_u<4>(t, kv.y, cb + 1, tauU);
    drain_u<4>(t, kv.z, cb + 2, tauU);
    drain_u<4>(t, kv.w, cb + 3, tauU);
  }
  if (lane < K_)
    idx[((size_t)b * P_ + row) * K_ + lane] = (int)(~(unsigned)t);
}

// ---------------- Kernel 5: e2 = x1@(W3a-W3b)+b3, bb2 = x1@W3b ----------
__global__ __launch_bounds__(256) void ebb_kernel(
    const float* __restrict__ x1, const float* __restrict__ W3,
    const float* __restrict__ b3, float* __restrict__ e2,
    float* __restrict__ bb2) {
  __shared__ float xs[16 * 64];
  size_t p0 = (size_t)blockIdx.x * 16;
  for (int v = threadIdx.x; v < 16 * 64; v += 256) xs[v] = x1[p0 * 64 + v];
  __syncthreads();
  int n = threadIdx.x & 127;
  int which = threadIdx.x >> 7;  // wave-uniform
  float acc[16];
#pragma unroll
  for (int p = 0; p < 16; ++p) acc[p] = 0.f;
  for (int c = 0; c < 64; ++c) {
    float wa = W3[c * 128 + n];
    float wb = W3[(64 + c) * 128 + n];
    float wv = which ? wb : (wa - wb);
#pragma unroll
    for (int p = 0; p < 16; ++p) acc[p] += xs[p * 64 + c] * wv;
  }
  float bias = which ? 0.f : b3[n];
  float* dst = which ? bb2 : e2;
#pragma unroll
  for (int p = 0; p < 16; ++p) dst[(p0 + p) * 128 + n] = acc[p] + bias;
}

// ---------------- Kernel 6: x2 gather-max + hp@Wl + per-tile max --------
__global__ __launch_bounds__(256) void final_kernel(
    const float* __restrict__ x1, const float* __restrict__ e2,
    const float* __restrict__ bb2, const int* __restrict__ idx,
    const float* __restrict__ Wl, const float* __restrict__ bl,
    float* __restrict__ partial) {
  __shared__ float hp[32][192];
  __shared__ float smax[2][128];
  int b = blockIdx.y;
  int i0 = blockIdx.x * 32;
  size_t gp0 = (size_t)b * P_ + i0;
  for (int v = threadIdx.x; v < 32 * 64; v += 256) {
    int p = v >> 6, c = v & 63;
    hp[p][c] = x1[(gp0 + p) * 64 + c];
  }
  for (int v = threadIdx.x; v < 32 * 128; v += 256) {
    int p = v >> 7, n = v & 127;
    size_t gp = gp0 + p;
    const int* ji = idx + gp * K_;
    float m = -INFINITY;
    for (int k = 0; k < K_; ++k) {
      int j = ji[k];
      m = fmaxf(m, bb2[((size_t)b * P_ + j) * 128 + n]);
    }
    hp[p][64 + n] = e2[gp * 128 + n] + m;
  }
  __syncthreads();
  int n = threadIdx.x & 127;
  int pg = threadIdx.x >> 7;
  float acc[16];
#pragma unroll
  for (int p = 0; p < 16; ++p) acc[p] = 0.f;
  for (int c = 0; c < 192; ++c) {
    float wv = Wl[c * 128 + n];
#pragma unroll
    for (int p = 0; p < 16; ++p) acc[p] += hp[pg * 16 + p][c] * wv;
  }
  float m = -INFINITY;
#pragma unroll
  for (int p = 0; p < 16; ++p) m = fmaxf(m, acc[p]);
  smax[pg][n] = m;
  __syncthreads();
  if (threadIdx.x < 128) {
    float v = fmaxf(smax[0][n], smax[1][n]) + bl[n];
    partial[((size_t)b * 64 + blockIdx.x) * 128 + n] = v;
  }
}

// ---------------- Kernel 7: reduce partial maxes -> out (B,128) ---------
__global__ __launch_bounds__(256) void reduce_kernel(
    const float* __restrict__ partial, float* __restrict__ out) {
  int t = blockIdx.x * 256 + threadIdx.x;  // 4096
  int b = t >> 7, n = t & 127;
  float m = -INFINITY;
  for (int tb = 0; tb < 64; ++tb)
    m = fmaxf(m, partial[((size_t)b * 64 + tb) * 128 + n]);
  out[t] = m;
}

extern "C" void kernel_launch(void* const* d_in, const int* in_sizes, int n_in,
                              void* d_out, int out_size, void* d_ws,
                              size_t ws_size, hipStream_t stream) {
  (void)in_sizes; (void)n_in; (void)out_size;
  const float* pos = (const float*)d_in[0];
  const float* W1  = (const float*)d_in[1];
  const float* b1  = (const float*)d_in[2];
  const float* g1  = (const float*)d_in[3];
  const float* bt1 = (const float*)d_in[4];
  const float* W2  = (const float*)d_in[5];
  const float* b2  = (const float*)d_in[6];
  const float* W3  = (const float*)d_in[7];
  const float* b3  = (const float*)d_in[8];
  const float* Wl  = (const float*)d_in[9];
  const float* bl  = (const float*)d_in[10];
  float* out = (float*)d_out;

  // Workspace layout (bytes), peak 90,439,680:
  //   [0, 5242880)          idx (idx1 then idx2)
  //   [5242880, 22020096)   x1
  //   [22020096, 22282240)  d2
  //   [22282240, 23330816)  partial
  //   [23330816, 90439680)  region (67,108,864): bv1 -> scores -> e2|bb2
  char* w = (char*)d_ws;
  int*      idxp  = (int*)(w + 0);
  float*    x1p   = (float*)(w + 5242880);
  float*    d2p   = (float*)(w + 22020096);
  float*    partp = (float*)(w + 22282240);
  float*    bv1p  = (float*)(w + 23330816);     // dead after layer1
  unsigned* scp   = (unsigned*)(w + 23330816);  // live only during kNN-2
  float*    e2p   = (float*)(w + 23330816);     // live after kNN-2
  float*    bb2p  = (float*)(w + 23330816 + 33554432);

  // Adaptive score-chunk: per batch 2048*2048*4 = 16,777,216 B.
  size_t avail = ws_size > 23330816 ? ws_size - 23330816 : 0;
  int chunkB = 4;  // guaranteed: region holds 4 x 16 MB
  if (avail >= (size_t)32 * 16777216) chunkB = 32;
  else if (avail >= (size_t)16 * 16777216) chunkB = 16;
  else if (avail >= (size_t)8 * 16777216) chunkB = 8;

  knn3_kernel<<<dim3(P_ / 64, B_), 512, 0, stream>>>(pos, idxp);
  bv1_kernel<<<dim3(B_ * P_ * 64 / 256), 256, 0, stream>>>(pos, W1, bv1p);
  layer1_kernel<<<dim3(P_ / 4, B_), 256, 0, stream>>>(
      pos, W1, b1, g1, bt1, W2, b2, idxp, bv1p, x1p, d2p);
  for (int cb = 0; cb < B_; cb += chunkB) {
    gemm_scores_kernel<<<dim3(32, 4, chunkB), 256, 0, stream>>>(
        x1p, d2p, scp, cb);
    knn_select_kernel<<<dim3(P_ / 4, chunkB), 256, 0, stream>>>(
        scp, idxp, cb);
  }
  ebb_kernel<<<dim3(B_ * P_ / 16), 256, 0, stream>>>(x1p, W3, b3, e2p, bb2p);
  final_kernel<<<dim3(P_ / 32, B_), 256, 0, stream>>>(
      x1p, e2p, bb2p, idxp, Wl, bl, partp);
  reduce_kernel<<<dim3(16), 256, 0, stream>>>(partp, out);
}

// Round 10
// 1001.308 us; speedup vs baseline: 2.8976x; 1.0179x over previous
//
#include <hip/hip_runtime.h>

#define B_ 32
#define P_ 2048
#define K_ 20

// ---- order-preserving (key, idx) packing -------------------------------
// larger key wins; ties -> smaller idx wins (matches jax.lax.top_k).
__device__ inline unsigned monok(float key) {
  unsigned u = __float_as_uint(key);
  return u ^ (((unsigned)((int)u >> 31)) | 0x80000000u);  // monotone f32->u32
}
__device__ inline float unmonok(unsigned u) {
  return __uint_as_float((u & 0x80000000u) ? (u ^ 0x80000000u) : ~u);
}
__device__ inline unsigned long long pack_key(float key, int j) {
  return ((unsigned long long)monok(key) << 32) | (unsigned)(~j);
}

// Full ascending bitonic sort of 64 u64 across the wave's lanes.
__device__ inline unsigned long long sort64(unsigned long long v, int lane) {
#pragma unroll
  for (int k = 2; k <= 64; k <<= 1) {
#pragma unroll
    for (int j = k >> 1; j > 0; j >>= 1) {
      unsigned long long o = __shfl_xor(v, j, 64);
      bool keepMin = ((lane & j) == 0) == ((lane & k) == 0);
      unsigned long long mn = v < o ? v : o;
      unsigned long long mx = v < o ? o : v;
      v = keepMin ? mn : mx;
    }
  }
  return v;
}

// Seed the wave-distributed top-20 list from 64 candidates (1/lane):
// sort ascending, move top-20 (lanes 44..63) to lanes 0..19, sentinel rest.
__device__ inline unsigned long long topk_seed(unsigned long long x, int lane) {
  unsigned long long s = sort64(x, lane);
  unsigned long long v = __shfl(s, lane + 44, 64);
  return (lane < K_) ? v : ~0ULL;
}

// ---- slim wave-distributed top-K drains --------------------------------
template <int STRIDE>
__device__ inline void drain_f(unsigned long long& t, float keyf, int jbase,
                               unsigned& tauU, float& tauf) {
  unsigned long long mask = __ballot(keyf >= tauf);
  while (mask) {
    int src = (int)__builtin_ctzll(mask);
    mask &= mask - 1;
    unsigned kb = (unsigned)__builtin_amdgcn_readlane(__float_as_int(keyf), src);
    unsigned kU = kb ^ (((unsigned)((int)kb >> 31)) | 0x80000000u);
    if (kU < tauU) continue;  // stale (scalar cmp+branch)
    unsigned long long xi =
        ((unsigned long long)kU << 32) | (unsigned)(~(jbase + src * STRIDE));
    unsigned long long up = __shfl_down(t, 1, 64);
    bool c1 = t < xi;
    bool c2 = up < xi;
    unsigned long long v = c1 ? xi : t;
    t = c2 ? up : v;
    tauU = (unsigned)__builtin_amdgcn_readlane((int)(unsigned)(t >> 32), 0);
    tauf = unmonok(tauU);
  }
}
template <int STRIDE>
__device__ inline void drain_u(unsigned long long& t, unsigned keyU, int jbase,
                               unsigned& tauU) {
  unsigned long long mask = __ballot(keyU >= tauU);
  while (mask) {
    int src = (int)__builtin_ctzll(mask);
    mask &= mask - 1;
    unsigned kU = (unsigned)__builtin_amdgcn_readlane((int)keyU, src);
    if (kU < tauU) continue;
    unsigned long long xi =
        ((unsigned long long)kU << 32) | (unsigned)(~(jbase + src * STRIDE));
    unsigned long long up = __shfl_down(t, 1, 64);
    bool c1 = t < xi;
    bool c2 = up < xi;
    unsigned long long v = c1 ? xi : t;
    t = c2 ? up : v;
    tauU = (unsigned)__builtin_amdgcn_readlane((int)(unsigned)(t >> 32), 0);
  }
}

// ---------------- Kernel 0: pts4[i] = (x, y, z, x^2+y^2+z^2) ------------
__global__ __launch_bounds__(256) void pts4_kernel(
    const float* __restrict__ pos, float4* __restrict__ pts4) {
  int i = blockIdx.x * 256 + threadIdx.x;  // over B*P
  const float* p = pos + (size_t)i * 3;
  float x = p[0], y = p[1], z = p[2];
  pts4[i] = make_float4(x, y, z, x * x + y * y + z * z);
}

// ---------------- Kernel 1: kNN on 3-D positions -> idx1 ----------------
// LDS-free: candidates read straight from global pts4 (L2-resident,
// coalesced 1KB/wave/chunk). Block 256 (4 waves), wave owns 4 rows ->
// pi fits registers (VGPR ~50 -> 8 waves/SIMD, no LDS residency cap).
__global__ __launch_bounds__(256) void knn3_kernel(
    const float4* __restrict__ pts4, int* __restrict__ idx) {
  int b = blockIdx.y;
  const float4* pb = pts4 + (size_t)b * P_;
  int wv = threadIdx.x >> 6;
  int lane = threadIdx.x & 63;
  int row0 = blockIdx.x * 16 + wv * 4;
  float4 pi[4];
#pragma unroll
  for (int rr = 0; rr < 4; ++rr) {
    float4 p = pb[row0 + rr];  // broadcast load
    pi[rr] = make_float4(2.f * p.x, 2.f * p.y, 2.f * p.z, p.w);
  }
  unsigned long long t[4];
  unsigned tauU[4];
  float tauf[4];
  // chunk 0: bitonic sort-seed
  {
    float4 pj = pb[lane];
#pragma unroll
    for (int rr = 0; rr < 4; ++rr) {
      float key = fmaf(pi[rr].x, pj.x,
                  fmaf(pi[rr].y, pj.y, fmaf(pi[rr].z, pj.z, -pj.w)));
      t[rr] = topk_seed(pack_key(key, lane), lane);
      tauU[rr] = (unsigned)__builtin_amdgcn_readlane(
          (int)(unsigned)(t[rr] >> 32), 0);
      tauf[rr] = unmonok(tauU[rr]);
    }
  }
#pragma unroll 1
  for (int ch = 1; ch < 32; ++ch) {
    float4 pj = pb[ch * 64 + lane];  // coalesced global (L2)
#pragma unroll
    for (int rr = 0; rr < 4; ++rr) {
      float key = fmaf(pi[rr].x, pj.x,
                  fmaf(pi[rr].y, pj.y, fmaf(pi[rr].z, pj.z, -pj.w)));
      drain_f<1>(t[rr], key, ch * 64, tauU[rr], tauf[rr]);
    }
  }
  if (lane < K_) {
#pragma unroll
    for (int rr = 0; rr < 4; ++rr)
      idx[((size_t)b * P_ + row0 + rr) * K_ + lane] = (int)(~(unsigned)t[rr]);
  }
}

// ---------------- Kernel 2: bv1[i][c] = pos_i @ W1[3:6] ----------------
__global__ __launch_bounds__(256) void bv1_kernel(
    const float* __restrict__ pos, const float* __restrict__ W1,
    float* __restrict__ bv) {
  int t = blockIdx.x * 256 + threadIdx.x;  // over B*P*64
  int c = t & 63, i = t >> 6;
  const float* p = pos + (size_t)i * 3;
  bv[t] = p[0] * W1[3 * 64 + c] + p[1] * W1[4 * 64 + c] + p[2] * W1[5 * 64 + c];
}

// ---------------- Kernel 3: layer-1 edge MLP + max over K -> x1, d2 -----
__global__ __launch_bounds__(256) void layer1_kernel(
    const float* __restrict__ pos, const float* __restrict__ W1,
    const float* __restrict__ b1, const float* __restrict__ g1,
    const float* __restrict__ bt1, const float* __restrict__ W2,
    const float* __restrict__ b2, const int* __restrict__ idx,
    const float* __restrict__ bv, float* __restrict__ x1,
    float* __restrict__ d2out) {
  __shared__ __align__(16) float W2t[64 * 68];  // W2t[n][c] = W2[c][n]
  __shared__ __align__(16) float T[4][K_ * 64];
  int b = blockIdx.y;
  int lane = threadIdx.x & 63;
  int w = threadIdx.x >> 6;
  for (int t = threadIdx.x; t < 64 * 64; t += 256) {
    int c = t >> 6, n = t & 63;
    W2t[n * 68 + c] = W2[c * 64 + n];
  }
  int i = blockIdx.x * 4 + w;
  size_t ip = (size_t)b * P_ + i;
  const float* posi = pos + ip * 3;
  float px = posi[0], py = posi[1], pz = posi[2];
  int c = lane;
  float cv = px * (W1[0 * 64 + c] - W1[3 * 64 + c]) +
             py * (W1[1 * 64 + c] - W1[4 * 64 + c]) +
             pz * (W1[2 * 64 + c] - W1[5 * 64 + c]) + b1[c];
  float g = g1[c], bt = bt1[c];
  const int* ji = idx + ip * K_;
  const float* bvb = bv + (size_t)b * P_ * 64;
  for (int k = 0; k < K_; ++k) {
    int j = ji[k];
    float t = cv + bvb[(size_t)j * 64 + c];
    t = fmaxf(t * g + bt, 0.f);
    T[w][k * 64 + c] = t;
  }
  __syncthreads();
  float acc[K_];
#pragma unroll
  for (int k = 0; k < K_; ++k) acc[k] = 0.f;
  const float4* Trow = (const float4*)&T[w][0];
#pragma unroll
  for (int c4 = 0; c4 < 16; ++c4) {
    float4 wv = *(const float4*)&W2t[lane * 68 + c4 * 4];
#pragma unroll
    for (int k = 0; k < K_; ++k) {
      float4 tvv = Trow[k * 16 + c4];  // broadcast
      acc[k] += tvv.x * wv.x + tvv.y * wv.y + tvv.z * wv.z + tvv.w * wv.w;
    }
  }
  float m = -INFINITY;
#pragma unroll
  for (int k = 0; k < K_; ++k) m = fmaxf(m, acc[k]);
  m += b2[lane];
  x1[ip * 64 + lane] = m;
  float s = m * m;
#pragma unroll
  for (int off = 32; off; off >>= 1) s += __shfl_xor(s, off, 64);
  if (lane == 0) d2out[ip] = s;
}

// ---------------- Kernel 4a: Gram scores -> packed u32 keys (global) ----
// grid (P/128, P/128, chunkB), block 256. 128x128 tile, K=64 staged once,
// 8x8 microtile (16 b128 reads per 64 FMA -> half the DS-cycles/element).
__global__ __launch_bounds__(256) void gemm_scores_kernel(
    const float* __restrict__ x1, const float* __restrict__ d2g,
    unsigned* __restrict__ scores, int chunkBase) {
  __shared__ __align__(16) float As[128 * 68];   // 34,816 B
  __shared__ __align__(16) float Bs[128 * 68];   // 34,816 B
  __shared__ float d2s[128];
  int bz = blockIdx.z;
  int b = chunkBase + bz;
  int r0 = blockIdx.x * 128;
  int c0 = blockIdx.y * 128;
  const float* xb = x1 + (size_t)b * P_ * 64;
  unsigned* sb = scores + ((size_t)bz * P_ + r0) * P_;
  int tid = threadIdx.x;
  int tr = tid >> 4;  // 0..15 -> rows tr*8+a
  int tc = tid & 15;  // cols tc+16*c

  for (int g = tid; g < 128 * 16; g += 256) {
    int r = g >> 4, c4 = g & 15;
    *(float4*)&As[r * 68 + c4 * 4] =
        *(const float4*)(xb + (size_t)(r0 + r) * 64 + c4 * 4);
  }
  for (int g = tid; g < 128 * 16; g += 256) {
    int r = g >> 4, c4 = g & 15;
    *(float4*)&Bs[r * 68 + c4 * 4] =
        *(const float4*)(xb + (size_t)(c0 + r) * 64 + c4 * 4);
  }
  if (tid < 128) d2s[tid] = d2g[(size_t)b * P_ + c0 + tid];
  __syncthreads();

  float acc[8][8];
#pragma unroll
  for (int a = 0; a < 8; ++a)
#pragma unroll
    for (int c = 0; c < 8; ++c) acc[a][c] = 0.f;
#pragma unroll
  for (int c4 = 0; c4 < 16; ++c4) {
    float4 af[8], bf[8];
#pragma unroll
    for (int a = 0; a < 8; ++a)
      af[a] = *(const float4*)(&As[(tr * 8 + a) * 68 + c4 * 4]);  // broadcast
#pragma unroll
    for (int c = 0; c < 8; ++c)
      bf[c] = *(const float4*)(&Bs[(tc + 16 * c) * 68 + c4 * 4]);  // 2-way
#pragma unroll
    for (int a = 0; a < 8; ++a)
#pragma unroll
      for (int c = 0; c < 8; ++c) {
        float s = acc[a][c];
        s = fmaf(af[a].x, bf[c].x, s);
        s = fmaf(af[a].y, bf[c].y, s);
        s = fmaf(af[a].z, bf[c].z, s);
        s = fmaf(af[a].w, bf[c].w, s);
        acc[a][c] = s;
      }
  }
#pragma unroll
  for (int a = 0; a < 8; ++a)
#pragma unroll
    for (int c = 0; c < 8; ++c) {
      int col = tc + 16 * c;
      sb[(size_t)(tr * 8 + a) * P_ + c0 + col] =
          monok(2.f * acc[a][c] - d2s[col]);
    }
}

// ---------------- Kernel 4b: select top-20 per row from key buffer ------
// grid (P/4, chunkB), block 256: one wave per row, no LDS.
__global__ __launch_bounds__(256) void knn_select_kernel(
    const unsigned* __restrict__ scores, int* __restrict__ idx,
    int chunkBase) {
  int bb = blockIdx.y;
  int b = chunkBase + bb;
  int row = blockIdx.x * 4 + (threadIdx.x >> 6);
  int lane = threadIdx.x & 63;
  const unsigned* sp = scores + ((size_t)bb * P_ + row) * P_;
  unsigned long long t;
  unsigned tauU;
  // it = 0: seed from first stripe (q==0), drain q=1..3
  {
    uint4 kv = *(const uint4*)(sp + lane * 4);
    t = topk_seed(((unsigned long long)kv.x << 32) | (unsigned)(~(lane * 4)),
                  lane);
    tauU = (unsigned)__builtin_amdgcn_readlane((int)(unsigned)(t >> 32), 0);
    drain_u<4>(t, kv.y, 1, tauU);
    drain_u<4>(t, kv.z, 2, tauU);
    drain_u<4>(t, kv.w, 3, tauU);
  }
#pragma unroll 1
  for (int it = 1; it < P_ / 256; ++it) {
    uint4 kv = *(const uint4*)(sp + it * 256 + lane * 4);
    int cb = it * 256;
    drain_u<4>(t, kv.x, cb + 0, tauU);
    drain_u<4>(t, kv.y, cb + 1, tauU);
    drain_u<4>(t, kv.z, cb + 2, tauU);
    drain_u<4>(t, kv.w, cb + 3, tauU);
  }
  if (lane < K_)
    idx[((size_t)b * P_ + row) * K_ + lane] = (int)(~(unsigned)t);
}

// ---------------- Kernel 5: e2 = x1@(W3a-W3b)+b3, bb2 = x1@W3b ----------
__global__ __launch_bounds__(256) void ebb_kernel(
    const float* __restrict__ x1, const float* __restrict__ W3,
    const float* __restrict__ b3, float* __restrict__ e2,
    float* __restrict__ bb2) {
  __shared__ float xs[16 * 64];
  size_t p0 = (size_t)blockIdx.x * 16;
  for (int v = threadIdx.x; v < 16 * 64; v += 256) xs[v] = x1[p0 * 64 + v];
  __syncthreads();
  int n = threadIdx.x & 127;
  int which = threadIdx.x >> 7;  // wave-uniform
  float acc[16];
#pragma unroll
  for (int p = 0; p < 16; ++p) acc[p] = 0.f;
  for (int c = 0; c < 64; ++c) {
    float wa = W3[c * 128 + n];
    float wb = W3[(64 + c) * 128 + n];
    float wv = which ? wb : (wa - wb);
#pragma unroll
    for (int p = 0; p < 16; ++p) acc[p] += xs[p * 64 + c] * wv;
  }
  float bias = which ? 0.f : b3[n];
  float* dst = which ? bb2 : e2;
#pragma unroll
  for (int p = 0; p < 16; ++p) dst[(p0 + p) * 128 + n] = acc[p] + bias;
}

// ---------------- Kernel 6: x2 gather-max + hp@Wl + per-tile max --------
__global__ __launch_bounds__(256) void final_kernel(
    const float* __restrict__ x1, const float* __restrict__ e2,
    const float* __restrict__ bb2, const int* __restrict__ idx,
    const float* __restrict__ Wl, const float* __restrict__ bl,
    float* __restrict__ partial) {
  __shared__ float hp[32][192];
  __shared__ float smax[2][128];
  int b = blockIdx.y;
  int i0 = blockIdx.x * 32;
  size_t gp0 = (size_t)b * P_ + i0;
  for (int v = threadIdx.x; v < 32 * 64; v += 256) {
    int p = v >> 6, c = v & 63;
    hp[p][c] = x1[(gp0 + p) * 64 + c];
  }
  for (int v = threadIdx.x; v < 32 * 128; v += 256) {
    int p = v >> 7, n = v & 127;
    size_t gp = gp0 + p;
    const int* ji = idx + gp * K_;
    float m = -INFINITY;
    for (int k = 0; k < K_; ++k) {
      int j = ji[k];
      m = fmaxf(m, bb2[((size_t)b * P_ + j) * 128 + n]);
    }
    hp[p][64 + n] = e2[gp * 128 + n] + m;
  }
  __syncthreads();
  int n = threadIdx.x & 127;
  int pg = threadIdx.x >> 7;
  float acc[16];
#pragma unroll
  for (int p = 0; p < 16; ++p) acc[p] = 0.f;
  for (int c = 0; c < 192; ++c) {
    float wv = Wl[c * 128 + n];
#pragma unroll
    for (int p = 0; p < 16; ++p) acc[p] += hp[pg * 16 + p][c] * wv;
  }
  float m = -INFINITY;
#pragma unroll
  for (int p = 0; p < 16; ++p) m = fmaxf(m, acc[p]);
  smax[pg][n] = m;
  __syncthreads();
  if (threadIdx.x < 128) {
    float v = fmaxf(smax[0][n], smax[1][n]) + bl[n];
    partial[((size_t)b * 64 + blockIdx.x) * 128 + n] = v;
  }
}

// ---------------- Kernel 7: reduce partial maxes -> out (B,128) ---------
__global__ __launch_bounds__(256) void reduce_kernel(
    const float* __restrict__ partial, float* __restrict__ out) {
  int t = blockIdx.x * 256 + threadIdx.x;  // 4096
  int b = t >> 7, n = t & 127;
  float m = -INFINITY;
  for (int tb = 0; tb < 64; ++tb)
    m = fmaxf(m, partial[((size_t)b * 64 + tb) * 128 + n]);
  out[t] = m;
}

extern "C" void kernel_launch(void* const* d_in, const int* in_sizes, int n_in,
                              void* d_out, int out_size, void* d_ws,
                              size_t ws_size, hipStream_t stream) {
  (void)in_sizes; (void)n_in; (void)out_size;
  const float* pos = (const float*)d_in[0];
  const float* W1  = (const float*)d_in[1];
  const float* b1  = (const float*)d_in[2];
  const float* g1  = (const float*)d_in[3];
  const float* bt1 = (const float*)d_in[4];
  const float* W2  = (const float*)d_in[5];
  const float* b2  = (const float*)d_in[6];
  const float* W3  = (const float*)d_in[7];
  const float* b3  = (const float*)d_in[8];
  const float* Wl  = (const float*)d_in[9];
  const float* bl  = (const float*)d_in[10];
  float* out = (float*)d_out;

  // Workspace layout (bytes), peak 90,439,680:
  //   [0, 5242880)          idx (idx1 then idx2)
  //   [5242880, 22020096)   x1
  //   [22020096, 22282240)  d2
  //   [22282240, 23330816)  partial
  //   [23330816, 90439680)  region: pts4 -> bv1 -> scores -> e2|bb2
  char* w = (char*)d_ws;
  int*      idxp  = (int*)(w + 0);
  float*    x1p   = (float*)(w + 5242880);
  float*    d2p   = (float*)(w + 22020096);
  float*    partp = (float*)(w + 22282240);
  float4*   pts4p = (float4*)(w + 23330816);    // live only during knn3
  float*    bv1p  = (float*)(w + 23330816);     // dead after layer1
  unsigned* scp   = (unsigned*)(w + 23330816);  // live only during kNN-2
  float*    e2p   = (float*)(w + 23330816);     // live after kNN-2
  float*    bb2p  = (float*)(w + 23330816 + 33554432);

  // Adaptive score-chunk: per batch 2048*2048*4 = 16,777,216 B.
  size_t avail = ws_size > 23330816 ? ws_size - 23330816 : 0;
  int chunkB = 4;  // guaranteed: region holds 4 x 16 MB
  if (avail >= (size_t)32 * 16777216) chunkB = 32;
  else if (avail >= (size_t)16 * 16777216) chunkB = 16;
  else if (avail >= (size_t)8 * 16777216) chunkB = 8;

  pts4_kernel<<<dim3(B_ * P_ / 256), 256, 0, stream>>>(pos, pts4p);
  knn3_kernel<<<dim3(P_ / 16, B_), 256, 0, stream>>>(pts4p, idxp);
  bv1_kernel<<<dim3(B_ * P_ * 64 / 256), 256, 0, stream>>>(pos, W1, bv1p);
  layer1_kernel<<<dim3(P_ / 4, B_), 256, 0, stream>>>(
      pos, W1, b1, g1, bt1, W2, b2, idxp, bv1p, x1p, d2p);
  for (int cb = 0; cb < B_; cb += chunkB) {
    gemm_scores_kernel<<<dim3(P_ / 128, P_ / 128, chunkB), 256, 0, stream>>>(
        x1p, d2p, scp, cb);
    knn_select_kernel<<<dim3(P_ / 4, chunkB), 256, 0, stream>>>(
        scp, idxp, cb);
  }
  ebb_kernel<<<dim3(B_ * P_ / 16), 256, 0, stream>>>(x1p, W3, b3, e2p, bb2p);
  final_kernel<<<dim3(P_ / 32, B_), 256, 0, stream>>>(
      x1p, e2p, bb2p, idxp, Wl, bl, partp);
  reduce_kernel<<<dim3(16), 256, 0, stream>>>(partp, out);
}

// Round 11
// 954.914 us; speedup vs baseline: 3.0383x; 1.0486x over previous
//
#include <hip/hip_runtime.h>

#define B_ 32
#define P_ 2048
#define K_ 20

// ---- order-preserving (key, idx) packing -------------------------------
// larger key wins; ties -> smaller idx wins (matches jax.lax.top_k).
__device__ inline unsigned monok(float key) {
  unsigned u = __float_as_uint(key);
  return u ^ (((unsigned)((int)u >> 31)) | 0x80000000u);  // monotone f32->u32
}
__device__ inline float unmonok(unsigned u) {
  return __uint_as_float((u & 0x80000000u) ? (u ^ 0x80000000u) : ~u);
}
__device__ inline unsigned long long pack_key(float key, int j) {
  return ((unsigned long long)monok(key) << 32) | (unsigned)(~j);
}

// Full ascending bitonic sort of 64 u64 across the wave's lanes.
__device__ inline unsigned long long sort64(unsigned long long v, int lane) {
#pragma unroll
  for (int k = 2; k <= 64; k <<= 1) {
#pragma unroll
    for (int j = k >> 1; j > 0; j >>= 1) {
      unsigned long long o = __shfl_xor(v, j, 64);
      bool keepMin = ((lane & j) == 0) == ((lane & k) == 0);
      unsigned long long mn = v < o ? v : o;
      unsigned long long mx = v < o ? o : v;
      v = keepMin ? mn : mx;
    }
  }
  return v;
}

// Seed the wave-distributed top-20 list from 64 candidates (1/lane):
// sort ascending, move top-20 (lanes 44..63) to lanes 0..19, sentinel rest.
__device__ inline unsigned long long topk_seed(unsigned long long x, int lane) {
  unsigned long long s = sort64(x, lane);
  unsigned long long v = __shfl(s, lane + 44, 64);
  return (lane < K_) ? v : ~0ULL;
}

// ---- slim wave-distributed top-K drains --------------------------------
template <int STRIDE>
__device__ inline void drain_f(unsigned long long& t, float keyf, int jbase,
                               unsigned& tauU, float& tauf) {
  unsigned long long mask = __ballot(keyf >= tauf);
  while (mask) {
    int src = (int)__builtin_ctzll(mask);
    mask &= mask - 1;
    unsigned kb = (unsigned)__builtin_amdgcn_readlane(__float_as_int(keyf), src);
    unsigned kU = kb ^ (((unsigned)((int)kb >> 31)) | 0x80000000u);
    if (kU < tauU) continue;  // stale (scalar cmp+branch)
    unsigned long long xi =
        ((unsigned long long)kU << 32) | (unsigned)(~(jbase + src * STRIDE));
    unsigned long long up = __shfl_down(t, 1, 64);
    bool c1 = t < xi;
    bool c2 = up < xi;
    unsigned long long v = c1 ? xi : t;
    t = c2 ? up : v;
    tauU = (unsigned)__builtin_amdgcn_readlane((int)(unsigned)(t >> 32), 0);
    tauf = unmonok(tauU);
  }
}
template <int STRIDE>
__device__ inline void drain_u(unsigned long long& t, unsigned keyU, int jbase,
                               unsigned& tauU) {
  unsigned long long mask = __ballot(keyU >= tauU);
  while (mask) {
    int src = (int)__builtin_ctzll(mask);
    mask &= mask - 1;
    unsigned kU = (unsigned)__builtin_amdgcn_readlane((int)keyU, src);
    if (kU < tauU) continue;
    unsigned long long xi =
        ((unsigned long long)kU << 32) | (unsigned)(~(jbase + src * STRIDE));
    unsigned long long up = __shfl_down(t, 1, 64);
    bool c1 = t < xi;
    bool c2 = up < xi;
    unsigned long long v = c1 ? xi : t;
    t = c2 ? up : v;
    tauU = (unsigned)__builtin_amdgcn_readlane((int)(unsigned)(t >> 32), 0);
  }
}

// ---------------- Kernel 0: pts4[i] = (x, y, z, x^2+y^2+z^2) ------------
__global__ __launch_bounds__(256) void pts4_kernel(
    const float* __restrict__ pos, float4* __restrict__ pts4) {
  int i = blockIdx.x * 256 + threadIdx.x;  // over B*P
  const float* p = pos + (size_t)i * 3;
  float x = p[0], y = p[1], z = p[2];
  pts4[i] = make_float4(x, y, z, x * x + y * y + z * z);
}

// ---------------- Kernel 1: kNN on 3-D positions -> idx1 ----------------
// LDS-free: candidates read straight from global pts4 (L2-resident,
// coalesced 1KB/wave/chunk). Block 256 (4 waves), wave owns 4 rows.
__global__ __launch_bounds__(256) void knn3_kernel(
    const float4* __restrict__ pts4, int* __restrict__ idx) {
  int b = blockIdx.y;
  const float4* pb = pts4 + (size_t)b * P_;
  int wv = threadIdx.x >> 6;
  int lane = threadIdx.x & 63;
  int row0 = blockIdx.x * 16 + wv * 4;
  float4 pi[4];
#pragma unroll
  for (int rr = 0; rr < 4; ++rr) {
    float4 p = pb[row0 + rr];  // broadcast load
    pi[rr] = make_float4(2.f * p.x, 2.f * p.y, 2.f * p.z, p.w);
  }
  unsigned long long t[4];
  unsigned tauU[4];
  float tauf[4];
  // chunk 0: bitonic sort-seed
  {
    float4 pj = pb[lane];
#pragma unroll
    for (int rr = 0; rr < 4; ++rr) {
      float key = fmaf(pi[rr].x, pj.x,
                  fmaf(pi[rr].y, pj.y, fmaf(pi[rr].z, pj.z, -pj.w)));
      t[rr] = topk_seed(pack_key(key, lane), lane);
      tauU[rr] = (unsigned)__builtin_amdgcn_readlane(
          (int)(unsigned)(t[rr] >> 32), 0);
      tauf[rr] = unmonok(tauU[rr]);
    }
  }
#pragma unroll 1
  for (int ch = 1; ch < 32; ++ch) {
    float4 pj = pb[ch * 64 + lane];  // coalesced global (L2)
#pragma unroll
    for (int rr = 0; rr < 4; ++rr) {
      float key = fmaf(pi[rr].x, pj.x,
                  fmaf(pi[rr].y, pj.y, fmaf(pi[rr].z, pj.z, -pj.w)));
      drain_f<1>(t[rr], key, ch * 64, tauU[rr], tauf[rr]);
    }
  }
  if (lane < K_) {
#pragma unroll
    for (int rr = 0; rr < 4; ++rr)
      idx[((size_t)b * P_ + row0 + rr) * K_ + lane] = (int)(~(unsigned)t[rr]);
  }
}

// ---------------- Kernel 3: layer-1 edge MLP + max over K -> x1, d2 -----
// grid (P/4, B), block 256 (4 waves, one point per wave in phase 1).
// Phase 1: T[p*20+k][c] = relu((cv_i[c] + pos_j@W1[3:6][c])*g1+bt1), bv
//          computed ON THE FLY (no bv buffer, no HBM gather).
// Phase 2: block GEMM A[80x64] @ W2t -> 16x16 thread microtiles (5 rows x
//          4 cols each), conflict-free stride-68 LDS.
// Epilogue: 5-row partial max -> pmax LDS -> per-point max + b2 -> x1, d2.
__global__ __launch_bounds__(256) void layer1_kernel(
    const float* __restrict__ pos, const float* __restrict__ W1,
    const float* __restrict__ b1, const float* __restrict__ g1,
    const float* __restrict__ bt1, const float* __restrict__ W2,
    const float* __restrict__ b2, const int* __restrict__ idx,
    float* __restrict__ x1, float* __restrict__ d2out) {
  __shared__ __align__(16) float W2t[64 * 68];  // W2t[n][c] = W2[c][n]
  __shared__ __align__(16) float A[80 * 68];    // T rows: p*20+k
  __shared__ float pmax[4][4][64];
  int b = blockIdx.y;
  int tid = threadIdx.x;
  int lane = tid & 63;
  int w = tid >> 6;
  for (int t = tid; t < 64 * 64; t += 256) {
    int c = t >> 6, n = t & 63;
    W2t[n * 68 + c] = W2[c * 64 + n];
  }
  int i = blockIdx.x * 4 + w;
  size_t ip = (size_t)b * P_ + i;
  const float* posi = pos + ip * 3;
  float px = posi[0], py = posi[1], pz = posi[2];
  int c = lane;
  float w3 = W1[3 * 64 + c], w4 = W1[4 * 64 + c], w5 = W1[5 * 64 + c];
  float cv = px * (W1[0 * 64 + c] - w3) + py * (W1[1 * 64 + c] - w4) +
             pz * (W1[2 * 64 + c] - w5) + b1[c];
  float g = g1[c], bt = bt1[c];
  const int* ji = idx + ip * K_;
  const float* posb = pos + (size_t)b * P_ * 3;
  for (int k = 0; k < K_; ++k) {
    int j = ji[k];  // broadcast
    const float* pj = posb + (size_t)j * 3;
    float xj = pj[0], yj = pj[1], zj = pj[2];  // broadcast loads (L1)
    float t = cv + fmaf(xj, w3, fmaf(yj, w4, zj * w5));
    t = fmaxf(fmaf(t, g, bt), 0.f);
    A[(w * K_ + k) * 68 + c] = t;  // lane-stride-1 write
  }
  __syncthreads();

  // ---- GEMM phase: A[80x64] @ W2t[64x64] ----
  int tr = tid >> 4;  // 0..15 -> rows tr*5..tr*5+4 (point p = tr>>2)
  int tc = tid & 15;  // cols tc + 16*cc
  float acc[5][4];
#pragma unroll
  for (int a = 0; a < 5; ++a)
#pragma unroll
    for (int cc = 0; cc < 4; ++cc) acc[a][cc] = 0.f;
#pragma unroll
  for (int c4 = 0; c4 < 16; ++c4) {
    float4 af[5], bf[4];
#pragma unroll
    for (int a = 0; a < 5; ++a)
      af[a] = *(const float4*)(&A[(tr * 5 + a) * 68 + c4 * 4]);
#pragma unroll
    for (int cc = 0; cc < 4; ++cc)
      bf[cc] = *(const float4*)(&W2t[(tc + 16 * cc) * 68 + c4 * 4]);
#pragma unroll
    for (int a = 0; a < 5; ++a)
#pragma unroll
      for (int cc = 0; cc < 4; ++cc) {
        float s = acc[a][cc];
        s = fmaf(af[a].x, bf[cc].x, s);
        s = fmaf(af[a].y, bf[cc].y, s);
        s = fmaf(af[a].z, bf[cc].z, s);
        s = fmaf(af[a].w, bf[cc].w, s);
        acc[a][cc] = s;
      }
  }
  // 5-row partial max per col
#pragma unroll
  for (int cc = 0; cc < 4; ++cc) {
    float m = acc[0][cc];
#pragma unroll
    for (int a = 1; a < 5; ++a) m = fmaxf(m, acc[a][cc]);
    pmax[tr >> 2][tr & 3][tc + 16 * cc] = m;
  }
  __syncthreads();

  // Epilogue: thread t -> point p = t>>6 (== its wave), col = t&63
  {
    int p = tid >> 6, col = tid & 63;
    float m = fmaxf(fmaxf(pmax[p][0][col], pmax[p][1][col]),
                    fmaxf(pmax[p][2][col], pmax[p][3][col]));
    m += b2[col];
    size_t ipp = (size_t)b * P_ + blockIdx.x * 4 + p;
    x1[ipp * 64 + col] = m;
    float s = m * m;
#pragma unroll
    for (int off = 32; off; off >>= 1) s += __shfl_xor(s, off, 64);
    if (col == 0) d2out[ipp] = s;
  }
}

// ---------------- Kernel 4a: Gram scores -> packed u32 keys (global) ----
// grid (P/128, P/128, chunkB), block 256. 128x128 tile, K=64 staged once,
// 8x8 microtile.
__global__ __launch_bounds__(256) void gemm_scores_kernel(
    const float* __restrict__ x1, const float* __restrict__ d2g,
    unsigned* __restrict__ scores, int chunkBase) {
  __shared__ __align__(16) float As[128 * 68];   // 34,816 B
  __shared__ __align__(16) float Bs[128 * 68];   // 34,816 B
  __shared__ float d2s[128];
  int bz = blockIdx.z;
  int b = chunkBase + bz;
  int r0 = blockIdx.x * 128;
  int c0 = blockIdx.y * 128;
  const float* xb = x1 + (size_t)b * P_ * 64;
  unsigned* sb = scores + ((size_t)bz * P_ + r0) * P_;
  int tid = threadIdx.x;
  int tr = tid >> 4;  // 0..15 -> rows tr*8+a
  int tc = tid & 15;  // cols tc+16*c

  for (int g = tid; g < 128 * 16; g += 256) {
    int r = g >> 4, c4 = g & 15;
    *(float4*)&As[r * 68 + c4 * 4] =
        *(const float4*)(xb + (size_t)(r0 + r) * 64 + c4 * 4);
  }
  for (int g = tid; g < 128 * 16; g += 256) {
    int r = g >> 4, c4 = g & 15;
    *(float4*)&Bs[r * 68 + c4 * 4] =
        *(const float4*)(xb + (size_t)(c0 + r) * 64 + c4 * 4);
  }
  if (tid < 128) d2s[tid] = d2g[(size_t)b * P_ + c0 + tid];
  __syncthreads();

  float acc[8][8];
#pragma unroll
  for (int a = 0; a < 8; ++a)
#pragma unroll
    for (int c = 0; c < 8; ++c) acc[a][c] = 0.f;
#pragma unroll
  for (int c4 = 0; c4 < 16; ++c4) {
    float4 af[8], bf[8];
#pragma unroll
    for (int a = 0; a < 8; ++a)
      af[a] = *(const float4*)(&As[(tr * 8 + a) * 68 + c4 * 4]);  // broadcast
#pragma unroll
    for (int c = 0; c < 8; ++c)
      bf[c] = *(const float4*)(&Bs[(tc + 16 * c) * 68 + c4 * 4]);  // 2-way
#pragma unroll
    for (int a = 0; a < 8; ++a)
#pragma unroll
      for (int c = 0; c < 8; ++c) {
        float s = acc[a][c];
        s = fmaf(af[a].x, bf[c].x, s);
        s = fmaf(af[a].y, bf[c].y, s);
        s = fmaf(af[a].z, bf[c].z, s);
        s = fmaf(af[a].w, bf[c].w, s);
        acc[a][c] = s;
      }
  }
#pragma unroll
  for (int a = 0; a < 8; ++a)
#pragma unroll
    for (int c = 0; c < 8; ++c) {
      int col = tc + 16 * c;
      sb[(size_t)(tr * 8 + a) * P_ + c0 + col] =
          monok(2.f * acc[a][c] - d2s[col]);
    }
}

// ---------------- Kernel 4b: select top-20 per row from key buffer ------
// grid (P/4, chunkB), block 256: one wave per row, no LDS.
__global__ __launch_bounds__(256) void knn_select_kernel(
    const unsigned* __restrict__ scores, int* __restrict__ idx,
    int chunkBase) {
  int bb = blockIdx.y;
  int b = chunkBase + bb;
  int row = blockIdx.x * 4 + (threadIdx.x >> 6);
  int lane = threadIdx.x & 63;
  const unsigned* sp = scores + ((size_t)bb * P_ + row) * P_;
  unsigned long long t;
  unsigned tauU;
  // it = 0: seed from first stripe (q==0), drain q=1..3
  {
    uint4 kv = *(const uint4*)(sp + lane * 4);
    t = topk_seed(((unsigned long long)kv.x << 32) | (unsigned)(~(lane * 4)),
                  lane);
    tauU = (unsigned)__builtin_amdgcn_readlane((int)(unsigned)(t >> 32), 0);
    drain_u<4>(t, kv.y, 1, tauU);
    drain_u<4>(t, kv.z, 2, tauU);
    drain_u<4>(t, kv.w, 3, tauU);
  }
#pragma unroll 1
  for (int it = 1; it < P_ / 256; ++it) {
    uint4 kv = *(const uint4*)(sp + it * 256 + lane * 4);
    int cb = it * 256;
    drain_u<4>(t, kv.x, cb + 0, tauU);
    drain_u<4>(t, kv.y, cb + 1, tauU);
    drain_u<4>(t, kv.z, cb + 2, tauU);
    drain_u<4>(t, kv.w, cb + 3, tauU);
  }
  if (lane < K_)
    idx[((size_t)b * P_ + row) * K_ + lane] = (int)(~(unsigned)t);
}

// ---------------- Kernel 5: e2 = x1@(W3a-W3b)+b3, bb2 = x1@W3b ----------
__global__ __launch_bounds__(256) void ebb_kernel(
    const float* __restrict__ x1, const float* __restrict__ W3,
    const float* __restrict__ b3, float* __restrict__ e2,
    float* __restrict__ bb2) {
  __shared__ float xs[16 * 64];
  size_t p0 = (size_t)blockIdx.x * 16;
  for (int v = threadIdx.x; v < 16 * 64; v += 256) xs[v] = x1[p0 * 64 + v];
  __syncthreads();
  int n = threadIdx.x & 127;
  int which = threadIdx.x >> 7;  // wave-uniform
  float acc[16];
#pragma unroll
  for (int p = 0; p < 16; ++p) acc[p] = 0.f;
  for (int c = 0; c < 64; ++c) {
    float wa = W3[c * 128 + n];
    float wb = W3[(64 + c) * 128 + n];
    float wv = which ? wb : (wa - wb);
#pragma unroll
    for (int p = 0; p < 16; ++p) acc[p] += xs[p * 64 + c] * wv;
  }
  float bias = which ? 0.f : b3[n];
  float* dst = which ? bb2 : e2;
#pragma unroll
  for (int p = 0; p < 16; ++p) dst[(p0 + p) * 128 + n] = acc[p] + bias;
}

// ---------------- Kernel 6: x2 gather-max + hp@Wl + per-tile max --------
__global__ __launch_bounds__(256) void final_kernel(
    const float* __restrict__ x1, const float* __restrict__ e2,
    const float* __restrict__ bb2, const int* __restrict__ idx,
    const float* __restrict__ Wl, const float* __restrict__ bl,
    float* __restrict__ partial) {
  __shared__ float hp[32][192];
  __shared__ float smax[2][128];
  int b = blockIdx.y;
  int i0 = blockIdx.x * 32;
  size_t gp0 = (size_t)b * P_ + i0;
  for (int v = threadIdx.x; v < 32 * 64; v += 256) {
    int p = v >> 6, c = v & 63;
    hp[p][c] = x1[(gp0 + p) * 64 + c];
  }
  for (int v = threadIdx.x; v < 32 * 128; v += 256) {
    int p = v >> 7, n = v & 127;
    size_t gp = gp0 + p;
    const int* ji = idx + gp * K_;
    float m = -INFINITY;
    for (int k = 0; k < K_; ++k) {
      int j = ji[k];
      m = fmaxf(m, bb2[((size_t)b * P_ + j) * 128 + n]);
    }
    hp[p][64 + n] = e2[gp * 128 + n] + m;
  }
  __syncthreads();
  int n = threadIdx.x & 127;
  int pg = threadIdx.x >> 7;
  float acc[16];
#pragma unroll
  for (int p = 0; p < 16; ++p) acc[p] = 0.f;
  for (int c = 0; c < 192; ++c) {
    float wv = Wl[c * 128 + n];
#pragma unroll
    for (int p = 0; p < 16; ++p) acc[p] += hp[pg * 16 + p][c] * wv;
  }
  float m = -INFINITY;
#pragma unroll
  for (int p = 0; p < 16; ++p) m = fmaxf(m, acc[p]);
  smax[pg][n] = m;
  __syncthreads();
  if (threadIdx.x < 128) {
    float v = fmaxf(smax[0][n], smax[1][n]) + bl[n];
    partial[((size_t)b * 64 + blockIdx.x) * 128 + n] = v;
  }
}

// ---------------- Kernel 7: reduce partial maxes -> out (B,128) ---------
__global__ __launch_bounds__(256) void reduce_kernel(
    const float* __restrict__ partial, float* __restrict__ out) {
  int t = blockIdx.x * 256 + threadIdx.x;  // 4096
  int b = t >> 7, n = t & 127;
  float m = -INFINITY;
  for (int tb = 0; tb < 64; ++tb)
    m = fmaxf(m, partial[((size_t)b * 64 + tb) * 128 + n]);
  out[t] = m;
}

extern "C" void kernel_launch(void* const* d_in, const int* in_sizes, int n_in,
                              void* d_out, int out_size, void* d_ws,
                              size_t ws_size, hipStream_t stream) {
  (void)in_sizes; (void)n_in; (void)out_size;
  const float* pos = (const float*)d_in[0];
  const float* W1  = (const float*)d_in[1];
  const float* b1  = (const float*)d_in[2];
  const float* g1  = (const float*)d_in[3];
  const float* bt1 = (const float*)d_in[4];
  const float* W2  = (const float*)d_in[5];
  const float* b2  = (const float*)d_in[6];
  const float* W3  = (const float*)d_in[7];
  const float* b3  = (const float*)d_in[8];
  const float* Wl  = (const float*)d_in[9];
  const float* bl  = (const float*)d_in[10];
  float* out = (float*)d_out;

  // Workspace layout (bytes), peak 90,439,680:
  //   [0, 5242880)          idx (idx1 then idx2)
  //   [5242880, 22020096)   x1
  //   [22020096, 22282240)  d2
  //   [22282240, 23330816)  partial
  //   [23330816, 90439680)  region: pts4 -> scores -> e2|bb2
  char* w = (char*)d_ws;
  int*      idxp  = (int*)(w + 0);
  float*    x1p   = (float*)(w + 5242880);
  float*    d2p   = (float*)(w + 22020096);
  float*    partp = (float*)(w + 22282240);
  float4*   pts4p = (float4*)(w + 23330816);    // live only during knn3
  unsigned* scp   = (unsigned*)(w + 23330816);  // live only during kNN-2
  float*    e2p   = (float*)(w + 23330816);     // live after kNN-2
  float*    bb2p  = (float*)(w + 23330816 + 33554432);

  // Adaptive score-chunk: per batch 2048*2048*4 = 16,777,216 B.
  size_t avail = ws_size > 23330816 ? ws_size - 23330816 : 0;
  int chunkB = 4;  // guaranteed: region holds 4 x 16 MB
  if (avail >= (size_t)32 * 16777216) chunkB = 32;
  else if (avail >= (size_t)16 * 16777216) chunkB = 16;
  else if (avail >= (size_t)8 * 16777216) chunkB = 8;

  pts4_kernel<<<dim3(B_ * P_ / 256), 256, 0, stream>>>(pos, pts4p);
  knn3_kernel<<<dim3(P_ / 16, B_), 256, 0, stream>>>(pts4p, idxp);
  layer1_kernel<<<dim3(P_ / 4, B_), 256, 0, stream>>>(
      pos, W1, b1, g1, bt1, W2, b2, idxp, x1p, d2p);
  for (int cb = 0; cb < B_; cb += chunkB) {
    gemm_scores_kernel<<<dim3(P_ / 128, P_ / 128, chunkB), 256, 0, stream>>>(
        x1p, d2p, scp, cb);
    knn_select_kernel<<<dim3(P_ / 4, chunkB), 256, 0, stream>>>(
        scp, idxp, cb);
  }
  ebb_kernel<<<dim3(B_ * P_ / 16), 256, 0, stream>>>(x1p, W3, b3, e2p, bb2p);
  final_kernel<<<dim3(P_ / 32, B_), 256, 0, stream>>>(
      x1p, e2p, bb2p, idxp, Wl, bl, partp);
  reduce_kernel<<<dim3(16), 256, 0, stream>>>(partp, out);
}